// Round 1
// baseline (354.736 us; speedup 1.0000x reference)
//
#include <hip/hip_runtime.h>

#define DM 1024
#define NHEADS 16
#define NKVH 4
#define HDIM 64
#define NB 2
#define SEQ 2048
#define MTOK (NB*SEQ)

typedef __attribute__((ext_vector_type(4))) float f32x4;
typedef __attribute__((ext_vector_type(8))) short short8;
typedef unsigned short u16;
typedef unsigned int u32;

__device__ __forceinline__ float b2f(u16 u) {
  u32 i = ((u32)u) << 16; float f; __builtin_memcpy(&f, &i, 4); return f;
}
__device__ __forceinline__ u16 f2b(float f) {
  u32 i; __builtin_memcpy(&i, &f, 4);
  u32 r = i + 0x7fffu + ((i >> 16) & 1u);
  return (u16)(r >> 16);
}
__device__ __forceinline__ void gload16(const void* g, void* l) {
  __builtin_amdgcn_global_load_lds((const __attribute__((address_space(1))) u32*)g,
                                   (__attribute__((address_space(3))) u32*)l, 16, 0, 0);
}

// ---------------- fp32 -> bf16 convert ----------------
__global__ __launch_bounds__(256) void cvt_kernel(const float* __restrict__ src,
                                                  u16* __restrict__ dst, int n) {
  int i = (blockIdx.x * 256 + threadIdx.x) * 8;
  if (i + 8 > n) return;
  float4 a = *(const float4*)(src + i);
  float4 b = *(const float4*)(src + i + 4);
  uint4 pk;
  pk.x = (u32)f2b(a.x) | ((u32)f2b(a.y) << 16);
  pk.y = (u32)f2b(a.z) | ((u32)f2b(a.w) << 16);
  pk.z = (u32)f2b(b.x) | ((u32)f2b(b.y) << 16);
  pk.w = (u32)f2b(b.z) | ((u32)f2b(b.w) << 16);
  *(uint4*)(dst + i) = pk;
}

// ---------------- GEMM: C[M,N] = A[M,K] @ W[N,K]^T (bf16 in, MFMA) ----------------
// MODE 0: fp32 plain store to Out[M][N]
// MODE 1: bf16 store remapped to ((b*OH + h)*SEQ + s)*64 + d   (h = col/64, per-head layout)
template<int MODE, int OH>
__global__ __launch_bounds__(256) void gemm_bt(const u16* __restrict__ A, const u16* __restrict__ W,
                                               void* __restrict__ Out, int M, int N, int K) {
  __shared__ __attribute__((aligned(16))) u16 As[128 * 64];
  __shared__ __attribute__((aligned(16))) u16 Bs[128 * 64];
  const int tid = threadIdx.x;
  const int lane = tid & 63, w = tid >> 6;
  const int wr = w >> 1, wc = w & 1;
  const int lo = lane & 15, hi = lane >> 4;
  const int m0 = blockIdx.y * 128, n0 = blockIdx.x * 128;

  f32x4 acc[4][4];
#pragma unroll
  for (int i = 0; i < 4; i++)
#pragma unroll
    for (int j = 0; j < 4; j++) acc[i][j] = (f32x4){0.f, 0.f, 0.f, 0.f};

  const int crow = lane >> 3;       // 0..7
  const int ccol = (lane & 7) * 8;  // 0..56

  for (int k0 = 0; k0 < K; k0 += 64) {
#pragma unroll
    for (int cc = 0; cc < 4; ++cc) {
      int c = w * 4 + cc;  // chunk 0..15, 8 rows x 64 cols each
      gload16(A + (size_t)(m0 + c * 8 + crow) * K + k0 + ccol, &As[c * 512]);
      gload16(W + (size_t)(n0 + c * 8 + crow) * K + k0 + ccol, &Bs[c * 512]);
    }
    __syncthreads();
    short8 af[4][2], bfr[4][2];
#pragma unroll
    for (int mi = 0; mi < 4; mi++)
#pragma unroll
      for (int kk = 0; kk < 2; kk++)
        af[mi][kk] = *(const short8*)(&As[(wr * 64 + mi * 16 + lo) * 64 + kk * 32 + hi * 8]);
#pragma unroll
    for (int ni = 0; ni < 4; ni++)
#pragma unroll
      for (int kk = 0; kk < 2; kk++)
        bfr[ni][kk] = *(const short8*)(&Bs[(wc * 64 + ni * 16 + lo) * 64 + kk * 32 + hi * 8]);
#pragma unroll
    for (int mi = 0; mi < 4; mi++)
#pragma unroll
      for (int ni = 0; ni < 4; ni++) {
        acc[mi][ni] = __builtin_amdgcn_mfma_f32_16x16x32_bf16(af[mi][0], bfr[ni][0], acc[mi][ni], 0, 0, 0);
        acc[mi][ni] = __builtin_amdgcn_mfma_f32_16x16x32_bf16(af[mi][1], bfr[ni][1], acc[mi][ni], 0, 0, 0);
      }
    __syncthreads();
  }

#pragma unroll
  for (int mi = 0; mi < 4; mi++)
#pragma unroll
    for (int ni = 0; ni < 4; ni++)
#pragma unroll
      for (int r = 0; r < 4; r++) {
        int row = m0 + wr * 64 + mi * 16 + hi * 4 + r;  // C/D: row=(lane>>4)*4+reg
        int col = n0 + wc * 64 + ni * 16 + lo;          //      col=lane&15
        if (MODE == 0) {
          ((float*)Out)[(size_t)row * N + col] = acc[mi][ni][r];
        } else {
          int b = row >> 11, s = row & (SEQ - 1);
          int h = col >> 6, d = col & 63;
          ((u16*)Out)[((size_t)(b * OH + h) * SEQ + s) * 64 + d] = f2b(acc[mi][ni][r]);
        }
      }
}

// ---------------- RoPE (in-place on (bh, s, 64) bf16). SCALE folds ATTN_SCALE into Q ----------------
template<bool SCALE>
__global__ __launch_bounds__(256) void rope_kernel(u16* __restrict__ buf,
                                                   const float* __restrict__ cosb,
                                                   const float* __restrict__ sinb) {
  int idx = blockIdx.x * 256 + threadIdx.x;
  int d0 = (idx & 7) * 8;
  int s = (idx >> 3) & (SEQ - 1);
  u16* p = buf + (size_t)(idx >> 3) * 64 + d0;
  uint4 raw = *(const uint4*)p;
  u32 rw[4] = {raw.x, raw.y, raw.z, raw.w};
  float4 cv = *(const float4*)(cosb + s * 32 + (d0 >> 1));
  float4 sv = *(const float4*)(sinb + s * 32 + (d0 >> 1));
  float ca[4] = {cv.x, cv.y, cv.z, cv.w};
  float sa[4] = {sv.x, sv.y, sv.z, sv.w};
  u32 out[4];
#pragma unroll
  for (int t = 0; t < 4; t++) {
    float xr = b2f((u16)(rw[t] & 0xffff));
    float xi = b2f((u16)(rw[t] >> 16));
    float orr = xr * ca[t] - xi * sa[t];
    float oii = xr * sa[t] + xi * ca[t];
    if (SCALE) { orr *= 0.125f; oii *= 0.125f; }
    out[t] = (u32)f2b(orr) | ((u32)f2b(oii) << 16);
  }
  uint4 ov; ov.x = out[0]; ov.y = out[1]; ov.z = out[2]; ov.w = out[3];
  *(uint4*)p = ov;
}

// ---------------- V transpose: (b,kh,s,d) -> (b,kh,d,s) ----------------
__global__ __launch_bounds__(256) void transpose_v(const u16* __restrict__ Vp, u16* __restrict__ Vt) {
  __shared__ __attribute__((aligned(16))) u16 T[64][68];
  int bkh = blockIdx.x >> 5;   // 0..7
  int st = blockIdx.x & 31;    // s-tile of 64
  int t = threadIdx.x;
#pragma unroll
  for (int g = 0; g < 2; ++g) {
    int lin = g * 2048 + t * 8;
    int sr = lin >> 6;
    int dc = lin & 63;
    uint4 v = *(const uint4*)(Vp + ((size_t)bkh * SEQ + st * 64 + sr) * 64 + dc);
    u32 vv[4] = {v.x, v.y, v.z, v.w};
#pragma unroll
    for (int jj = 0; jj < 4; jj++) {
      T[dc + 2 * jj][sr] = (u16)(vv[jj] & 0xffff);
      T[dc + 2 * jj + 1][sr] = (u16)(vv[jj] >> 16);
    }
  }
  __syncthreads();
#pragma unroll
  for (int g = 0; g < 2; ++g) {
    int lin = g * 2048 + t * 8;
    int dr = lin >> 6;
    int sc2 = lin & 63;
    u32 ov[4];
#pragma unroll
    for (int jj = 0; jj < 4; jj++)
      ov[jj] = (u32)T[dr][sc2 + 2 * jj] | ((u32)T[dr][sc2 + 2 * jj + 1] << 16);
    uint4 q4; q4.x = ov[0]; q4.y = ov[1]; q4.z = ov[2]; q4.w = ov[3];
    *(uint4*)(Vt + ((size_t)bkh * 64 + dr) * SEQ + st * 64 + sc2) = q4;
  }
}

// ---------------- Flash attention (causal, GQA). Q pre-scaled by ATTN_SCALE ----------------
// Q: (b,h,s,d) bf16; K: (b,kh,s,d) bf16; Vt: (b,kh,d,s) bf16; AO: (b,s,h,d) bf16
__global__ __launch_bounds__(256) void attn_kernel(const u16* __restrict__ Q, const u16* __restrict__ Kb,
                                                   const u16* __restrict__ Vt, u16* __restrict__ AO) {
  __shared__ __attribute__((aligned(16))) u16 P[4][16][72];  // per-wave P tile (16q x 64kv)
  const int w = threadIdx.x >> 6, lane = threadIdx.x & 63;
  const int lo = lane & 15, hi = lane >> 4;
  const int bh = blockIdx.y;
  const int b = bh >> 4, h = bh & 15, kh = h >> 2;
  const int q0 = blockIdx.x * 64 + w * 16;  // this wave's 16 q rows
  const u16* Qp = Q + (size_t)bh * SEQ * 64;
  const u16* Kp = Kb + (size_t)(b * NKVH + kh) * SEQ * 64;
  const u16* Vp = Vt + (size_t)(b * NKVH + kh) * 64 * SEQ;
  const float L2E = 1.44269504088896f;

  short8 qf[2];
#pragma unroll
  for (int kk = 0; kk < 2; kk++)
    qf[kk] = *(const short8*)(Qp + (size_t)(q0 + lo) * 64 + kk * 32 + hi * 8);

  f32x4 o[4];
#pragma unroll
  for (int nf = 0; nf < 4; nf++) o[nf] = (f32x4){0.f, 0.f, 0.f, 0.f};
  float m[4], ls[4];
#pragma unroll
  for (int r = 0; r < 4; r++) { m[r] = -__builtin_inff(); ls[r] = 0.f; }

  u16 (*Pw)[72] = P[w];

  for (int kv0 = 0; kv0 <= q0 + 15; kv0 += 64) {
    // QK^T: scores 16q x 64kv.  A=Q (row=lo=q), B=K^T (col=lo=kv, k=d contiguous from K rows)
    f32x4 sc[4];
#pragma unroll
    for (int kf = 0; kf < 4; kf++) sc[kf] = (f32x4){0.f, 0.f, 0.f, 0.f};
#pragma unroll
    for (int kf = 0; kf < 4; kf++)
#pragma unroll
      for (int kk = 0; kk < 2; kk++) {
        short8 kfr = *(const short8*)(Kp + (size_t)(kv0 + kf * 16 + lo) * 64 + kk * 32 + hi * 8);
        sc[kf] = __builtin_amdgcn_mfma_f32_16x16x32_bf16(qf[kk], kfr, sc[kf], 0, 0, 0);
      }
    if (kv0 + 63 > q0) {  // straddling chunk: causal mask
#pragma unroll
      for (int kf = 0; kf < 4; kf++) {
        int kv = kv0 + kf * 16 + lo;
#pragma unroll
        for (int r = 0; r < 4; r++) {
          int q = q0 + hi * 4 + r;
          if (kv > q) sc[kf][r] = -__builtin_inff();
        }
      }
    }
    // online softmax (rows live in lanes sharing hi; reduce across the 16 lo lanes)
    float cm[4], rs[4], corr[4];
#pragma unroll
    for (int r = 0; r < 4; r++)
      cm[r] = fmaxf(fmaxf(sc[0][r], sc[1][r]), fmaxf(sc[2][r], sc[3][r]));
#pragma unroll
    for (int x = 1; x < 16; x <<= 1)
#pragma unroll
      for (int r = 0; r < 4; r++) cm[r] = fmaxf(cm[r], __shfl_xor(cm[r], x, 64));
#pragma unroll
    for (int r = 0; r < 4; r++) {
      float mn = fmaxf(m[r], cm[r]);
      corr[r] = exp2f((m[r] - mn) * L2E);
      m[r] = mn;
      rs[r] = 0.f;
    }
#pragma unroll
    for (int kf = 0; kf < 4; kf++)
#pragma unroll
      for (int r = 0; r < 4; r++) {
        float p = exp2f((sc[kf][r] - m[r]) * L2E);
        rs[r] += p;
        Pw[hi * 4 + r][kf * 16 + lo] = f2b(p);  // C-layout -> LDS
      }
#pragma unroll
    for (int x = 1; x < 16; x <<= 1)
#pragma unroll
      for (int r = 0; r < 4; r++) rs[r] += __shfl_xor(rs[r], x, 64);
#pragma unroll
    for (int r = 0; r < 4; r++) ls[r] = ls[r] * corr[r] + rs[r];
#pragma unroll
    for (int nf = 0; nf < 4; nf++) {
      o[nf][0] *= corr[0]; o[nf][1] *= corr[1]; o[nf][2] *= corr[2]; o[nf][3] *= corr[3];
    }
    // PV: A=P (row=lo=q, k=kv from LDS), B=V (col=lo->d via Vt rows, k=kv contiguous)
    short8 pa[2];
#pragma unroll
    for (int kk = 0; kk < 2; kk++)
      pa[kk] = *(const short8*)(&Pw[lo][kk * 32 + hi * 8]);
#pragma unroll
    for (int nf = 0; nf < 4; nf++)
#pragma unroll
      for (int kk = 0; kk < 2; kk++) {
        short8 vb = *(const short8*)(Vp + (size_t)(nf * 16 + lo) * SEQ + kv0 + kk * 32 + hi * 8);
        o[nf] = __builtin_amdgcn_mfma_f32_16x16x32_bf16(pa[kk], vb, o[nf], 0, 0, 0);
      }
  }
#pragma unroll
  for (int r = 0; r < 4; r++) ls[r] = 1.0f / ls[r];
#pragma unroll
  for (int nf = 0; nf < 4; nf++)
#pragma unroll
    for (int r = 0; r < 4; r++) {
      int q = q0 + hi * 4 + r;
      int d = nf * 16 + lo;
      AO[((size_t)(b * SEQ + q) * NHEADS + h) * 64 + d] = f2b(o[nf][r] * ls[r]);
    }
}

extern "C" void kernel_launch(void* const* d_in, const int* in_sizes, int n_in,
                              void* d_out, int out_size, void* d_ws, size_t ws_size,
                              hipStream_t stream) {
  const float* query = (const float*)d_in[0];
  const float* key_ = (const float*)d_in[1];
  const float* value = (const float*)d_in[2];
  const float* fcos = (const float*)d_in[3];
  const float* fsin = (const float*)d_in[4];
  const float* wq = (const float*)d_in[5];
  const float* wk = (const float*)d_in[6];
  const float* wv = (const float*)d_in[7];
  const float* wo = (const float*)d_in[8];

  char* ws = (char*)d_ws;
  size_t off = 0;
  auto alloc = [&](size_t elems) {
    u16* p = (u16*)(ws + off);
    off = (off + elems * 2 + 255) & ~(size_t)255;
    return p;
  };
  u16* qf = alloc((size_t)MTOK * DM);
  u16* kf = alloc((size_t)MTOK * DM);
  u16* vf = alloc((size_t)MTOK * DM);
  u16* wqf = alloc((size_t)DM * DM);
  u16* wkf = alloc((size_t)256 * DM);
  u16* wvf = alloc((size_t)256 * DM);
  u16* wof = alloc((size_t)DM * DM);
  u16* Qr = alloc((size_t)MTOK * DM);            // (b,h,s,d)
  u16* Kr = alloc((size_t)NB * NKVH * SEQ * 64); // (b,kh,s,d)
  u16* Vp = alloc((size_t)NB * NKVH * SEQ * 64); // (b,kh,s,d)
  u16* Vt = alloc((size_t)NB * NKVH * 64 * SEQ); // (b,kh,d,s)
  u16* AO = alloc((size_t)MTOK * DM);            // (b,s,h,d)

  cvt_kernel<<<(MTOK * DM) / 2048, 256, 0, stream>>>(query, qf, MTOK * DM);
  cvt_kernel<<<(MTOK * DM) / 2048, 256, 0, stream>>>(key_, kf, MTOK * DM);
  cvt_kernel<<<(MTOK * DM) / 2048, 256, 0, stream>>>(value, vf, MTOK * DM);
  cvt_kernel<<<(DM * DM) / 2048, 256, 0, stream>>>(wq, wqf, DM * DM);
  cvt_kernel<<<(256 * DM) / 2048, 256, 0, stream>>>(wk, wkf, 256 * DM);
  cvt_kernel<<<(256 * DM) / 2048, 256, 0, stream>>>(wv, wvf, 256 * DM);
  cvt_kernel<<<(DM * DM) / 2048, 256, 0, stream>>>(wo, wof, DM * DM);

  gemm_bt<1, NHEADS><<<dim3(DM / 128, MTOK / 128), 256, 0, stream>>>(qf, wqf, Qr, MTOK, DM, DM);
  gemm_bt<1, NKVH><<<dim3(2, MTOK / 128), 256, 0, stream>>>(kf, wkf, Kr, MTOK, 256, DM);
  gemm_bt<1, NKVH><<<dim3(2, MTOK / 128), 256, 0, stream>>>(vf, wvf, Vp, MTOK, 256, DM);

  rope_kernel<true><<<(NB * NHEADS * SEQ * 8) / 256, 256, 0, stream>>>(Qr, fcos, fsin);
  rope_kernel<false><<<(NB * NKVH * SEQ * 8) / 256, 256, 0, stream>>>(Kr, fcos, fsin);

  transpose_v<<<NB * NKVH * (SEQ / 64), 256, 0, stream>>>(Vp, Vt);

  attn_kernel<<<dim3(SEQ / 64, NB * NHEADS), 256, 0, stream>>>(Qr, Kr, Vt, AO);

  gemm_bt<0, 0><<<dim3(DM / 128, MTOK / 128), 256, 0, stream>>>(AO, wof, d_out, MTOK, DM, DM);
}

// Round 2
// 278.204 us; speedup vs baseline: 1.2751x; 1.2751x over previous
//
#include <hip/hip_runtime.h>

#define DM 1024
#define NHEADS 16
#define NKVH 4
#define HDIM 64
#define NB 2
#define SEQ 2048
#define MTOK (NB*SEQ)

typedef __attribute__((ext_vector_type(4))) float f32x4;
typedef __attribute__((ext_vector_type(8))) short short8;
typedef unsigned short u16;
typedef unsigned int u32;

__device__ __forceinline__ float b2f(u16 u) {
  u32 i = ((u32)u) << 16; float f; __builtin_memcpy(&f, &i, 4); return f;
}
__device__ __forceinline__ u16 f2b(float f) {
  u32 i; __builtin_memcpy(&i, &f, 4);
  u32 r = i + 0x7fffu + ((i >> 16) & 1u);
  return (u16)(r >> 16);
}
__device__ __forceinline__ void gload16(const void* g, void* l) {
  __builtin_amdgcn_global_load_lds((const __attribute__((address_space(1))) u32*)g,
                                   (__attribute__((address_space(3))) u32*)l, 16, 0, 0);
}

// ---------------- fp32 -> bf16 convert ----------------
__device__ __forceinline__ void cvt8(const float* __restrict__ src, u16* __restrict__ dst, int i) {
  float4 a = *(const float4*)(src + i);
  float4 b = *(const float4*)(src + i + 4);
  uint4 pk;
  pk.x = (u32)f2b(a.x) | ((u32)f2b(a.y) << 16);
  pk.y = (u32)f2b(a.z) | ((u32)f2b(a.w) << 16);
  pk.z = (u32)f2b(b.x) | ((u32)f2b(b.y) << 16);
  pk.w = (u32)f2b(b.z) | ((u32)f2b(b.w) << 16);
  *(uint4*)(dst + i) = pk;
}

// three equal-size tensors (q,k,v activations)
__global__ __launch_bounds__(256) void cvt3_kernel(const float* __restrict__ a, const float* __restrict__ b,
                                                   const float* __restrict__ c, u16* __restrict__ oa,
                                                   u16* __restrict__ ob, u16* __restrict__ oc) {
  int i = (blockIdx.x * 256 + threadIdx.x) * 8;
  const float* s = (blockIdx.y == 0) ? a : (blockIdx.y == 1) ? b : c;
  u16* d = (blockIdx.y == 0) ? oa : (blockIdx.y == 1) ? ob : oc;
  cvt8(s, d, i);
}

// all four weights in one launch: wq(DM*DM), wk(256*DM), wv(256*DM), wo(DM*DM)
__global__ __launch_bounds__(256) void cvtw_kernel(const float* __restrict__ wq, const float* __restrict__ wk,
                                                   const float* __restrict__ wv, const float* __restrict__ wo,
                                                   u16* __restrict__ oq, u16* __restrict__ ok,
                                                   u16* __restrict__ ov, u16* __restrict__ oo) {
  const int BIG = (DM * DM) / 2048;   // 512 blocks
  const int SML = (256 * DM) / 2048;  // 128 blocks
  int bid = blockIdx.x;
  const float* s; u16* d;
  if (bid < BIG) { s = wq; d = oq; }
  else if (bid < 2 * BIG) { s = wo; d = oo; bid -= BIG; }
  else if (bid < 2 * BIG + SML) { s = wk; d = ok; bid -= 2 * BIG; }
  else { s = wv; d = ov; bid -= 2 * BIG + SML; }
  cvt8(s, d, (bid * 256 + threadIdx.x) * 8);
}

// ---------------- GEMM: C[M,N] = A[M,K] @ W[N,K]^T (bf16 in, MFMA) ----------------
// MODE 0: fp32 plain store to Out[M][N]
// MODE 1: bf16 store remapped to ((b*OH + h)*SEQ + s)*64 + d   (h = col/64, per-head layout)
template<int MODE, int OH>
__global__ __launch_bounds__(256) void gemm_bt(const u16* __restrict__ A, const u16* __restrict__ W,
                                               void* __restrict__ Out, int M, int N, int K) {
  __shared__ __attribute__((aligned(16))) u16 As[128 * 64];
  __shared__ __attribute__((aligned(16))) u16 Bs[128 * 64];
  const int tid = threadIdx.x;
  const int lane = tid & 63, w = tid >> 6;
  const int wr = w >> 1, wc = w & 1;
  const int lo = lane & 15, hi = lane >> 4;
  const int m0 = blockIdx.y * 128, n0 = blockIdx.x * 128;

  f32x4 acc[4][4];
#pragma unroll
  for (int i = 0; i < 4; i++)
#pragma unroll
    for (int j = 0; j < 4; j++) acc[i][j] = (f32x4){0.f, 0.f, 0.f, 0.f};

  const int crow = lane >> 3;       // 0..7
  const int ccol = (lane & 7) * 8;  // 0..56

  for (int k0 = 0; k0 < K; k0 += 64) {
#pragma unroll
    for (int cc = 0; cc < 4; ++cc) {
      int c = w * 4 + cc;  // chunk 0..15, 8 rows x 64 cols each
      gload16(A + (size_t)(m0 + c * 8 + crow) * K + k0 + ccol, &As[c * 512]);
      gload16(W + (size_t)(n0 + c * 8 + crow) * K + k0 + ccol, &Bs[c * 512]);
    }
    __syncthreads();
    short8 af[4][2], bfr[4][2];
#pragma unroll
    for (int mi = 0; mi < 4; mi++)
#pragma unroll
      for (int kk = 0; kk < 2; kk++)
        af[mi][kk] = *(const short8*)(&As[(wr * 64 + mi * 16 + lo) * 64 + kk * 32 + hi * 8]);
#pragma unroll
    for (int ni = 0; ni < 4; ni++)
#pragma unroll
      for (int kk = 0; kk < 2; kk++)
        bfr[ni][kk] = *(const short8*)(&Bs[(wc * 64 + ni * 16 + lo) * 64 + kk * 32 + hi * 8]);
    __builtin_amdgcn_s_setprio(1);
#pragma unroll
    for (int mi = 0; mi < 4; mi++)
#pragma unroll
      for (int ni = 0; ni < 4; ni++) {
        acc[mi][ni] = __builtin_amdgcn_mfma_f32_16x16x32_bf16(af[mi][0], bfr[ni][0], acc[mi][ni], 0, 0, 0);
        acc[mi][ni] = __builtin_amdgcn_mfma_f32_16x16x32_bf16(af[mi][1], bfr[ni][1], acc[mi][ni], 0, 0, 0);
      }
    __builtin_amdgcn_s_setprio(0);
    __syncthreads();
  }

#pragma unroll
  for (int mi = 0; mi < 4; mi++)
#pragma unroll
    for (int ni = 0; ni < 4; ni++)
#pragma unroll
      for (int r = 0; r < 4; r++) {
        int row = m0 + wr * 64 + mi * 16 + hi * 4 + r;  // C/D: row=(lane>>4)*4+reg
        int col = n0 + wc * 64 + ni * 16 + lo;          //      col=lane&15
        if (MODE == 0) {
          ((float*)Out)[(size_t)row * N + col] = acc[mi][ni][r];
        } else {
          int b = row >> 11, s = row & (SEQ - 1);
          int h = col >> 6, d = col & 63;
          ((u16*)Out)[((size_t)(b * OH + h) * SEQ + s) * 64 + d] = f2b(acc[mi][ni][r]);
        }
      }
}

// ---------------- RoPE (in-place on (bh, s, 64) bf16). SCALE folds ATTN_SCALE*log2(e) into Q ----------------
template<bool SCALE>
__global__ __launch_bounds__(256) void rope_kernel(u16* __restrict__ buf,
                                                   const float* __restrict__ cosb,
                                                   const float* __restrict__ sinb) {
  int idx = blockIdx.x * 256 + threadIdx.x;
  int d0 = (idx & 7) * 8;
  int s = (idx >> 3) & (SEQ - 1);
  u16* p = buf + (size_t)(idx >> 3) * 64 + d0;
  uint4 raw = *(const uint4*)p;
  u32 rw[4] = {raw.x, raw.y, raw.z, raw.w};
  float4 cv = *(const float4*)(cosb + s * 32 + (d0 >> 1));
  float4 sv = *(const float4*)(sinb + s * 32 + (d0 >> 1));
  float ca[4] = {cv.x, cv.y, cv.z, cv.w};
  float sa[4] = {sv.x, sv.y, sv.z, sv.w};
  u32 out[4];
#pragma unroll
  for (int t = 0; t < 4; t++) {
    float xr = b2f((u16)(rw[t] & 0xffff));
    float xi = b2f((u16)(rw[t] >> 16));
    float orr = xr * ca[t] - xi * sa[t];
    float oii = xr * sa[t] + xi * ca[t];
    if (SCALE) { orr *= 0.18033688f; oii *= 0.18033688f; }  // (1/8) * log2(e)
    out[t] = (u32)f2b(orr) | ((u32)f2b(oii) << 16);
  }
  uint4 ov; ov.x = out[0]; ov.y = out[1]; ov.z = out[2]; ov.w = out[3];
  *(uint4*)p = ov;
}

// ---------------- V transpose: (b,kh,s,d) -> (b,kh,d,s) ----------------
__global__ __launch_bounds__(256) void transpose_v(const u16* __restrict__ Vp, u16* __restrict__ Vt) {
  __shared__ __attribute__((aligned(16))) u16 T[64][68];
  int bkh = blockIdx.x >> 5;   // 0..7
  int st = blockIdx.x & 31;    // s-tile of 64
  int t = threadIdx.x;
#pragma unroll
  for (int g = 0; g < 2; ++g) {
    int lin = g * 2048 + t * 8;
    int sr = lin >> 6;
    int dc = lin & 63;
    uint4 v = *(const uint4*)(Vp + ((size_t)bkh * SEQ + st * 64 + sr) * 64 + dc);
    u32 vv[4] = {v.x, v.y, v.z, v.w};
#pragma unroll
    for (int jj = 0; jj < 4; jj++) {
      T[dc + 2 * jj][sr] = (u16)(vv[jj] & 0xffff);
      T[dc + 2 * jj + 1][sr] = (u16)(vv[jj] >> 16);
    }
  }
  __syncthreads();
#pragma unroll
  for (int g = 0; g < 2; ++g) {
    int lin = g * 2048 + t * 8;
    int dr = lin >> 6;
    int sc2 = lin & 63;
    u32 ov[4];
#pragma unroll
    for (int jj = 0; jj < 4; jj++)
      ov[jj] = (u32)T[dr][sc2 + 2 * jj] | ((u32)T[dr][sc2 + 2 * jj + 1] << 16);
    uint4 q4; q4.x = ov[0]; q4.y = ov[1]; q4.z = ov[2]; q4.w = ov[3];
    *(uint4*)(Vt + ((size_t)bkh * 64 + dr) * SEQ + st * 64 + sc2) = q4;
  }
}

// ---------------- Flash attention (causal, GQA). Q pre-scaled by ATTN_SCALE*log2e ----------------
// Q: (b,h,s,d) bf16; K: (b,kh,s,d) bf16; Vt: (b,kh,d,s) bf16; AO: (b,s,h,d) bf16
// grid: x = bh (32), y = permuted q-tile (32).  Permutation makes the 4 tiles
// {y0, 15-y0, 16+y0, 31-y0} a CU receives sum to constant work (62 chunks).
__global__ __launch_bounds__(256, 4) void attn_kernel(const u16* __restrict__ Q, const u16* __restrict__ Kb,
                                                      const u16* __restrict__ Vt, u16* __restrict__ AO) {
  __shared__ __attribute__((aligned(16))) u16 P[4][16][72];  // per-wave P tile (16q x 64kv)
  const int w = threadIdx.x >> 6, lane = threadIdx.x & 63;
  const int lo = lane & 15, hi = lane >> 4;
  const int bh = blockIdx.x;
  const int b = bh >> 4, h = bh & 15, kh = h >> 2;
  const int y = blockIdx.y, y0 = y & 7, gq = y >> 3;
  const int tile = (gq == 0) ? y0 : (gq == 1) ? (15 - y0) : (gq == 2) ? (16 + y0) : (31 - y0);
  const int q0 = tile * 64 + w * 16;  // this wave's 16 q rows
  const u16* Qp = Q + (size_t)bh * SEQ * 64;
  const u16* Kp = Kb + (size_t)(b * NKVH + kh) * SEQ * 64;
  const u16* Vp = Vt + (size_t)(b * NKVH + kh) * 64 * SEQ;

  short8 qf[2];
#pragma unroll
  for (int kk = 0; kk < 2; kk++)
    qf[kk] = *(const short8*)(Qp + (size_t)(q0 + lo) * 64 + kk * 32 + hi * 8);

  f32x4 o[4];
#pragma unroll
  for (int nf = 0; nf < 4; nf++) o[nf] = (f32x4){0.f, 0.f, 0.f, 0.f};
  float m[4], ls[4];
#pragma unroll
  for (int r = 0; r < 4; r++) { m[r] = -__builtin_inff(); ls[r] = 0.f; }

  u16 (*Pw)[72] = P[w];
  const u16* Kl = Kp + lo * 64 + hi * 8;        // lane base into K rows
  const u16* Vl = Vp + (size_t)lo * SEQ + hi * 8;  // lane base into Vt rows

  const int nt = tile + 1;  // 64-kv chunks (same for all 4 waves in block)
  short8 kcur[4][2];
#pragma unroll
  for (int kf = 0; kf < 4; kf++)
#pragma unroll
    for (int kk = 0; kk < 2; kk++)
      kcur[kf][kk] = *(const short8*)(Kl + kf * 16 * 64 + kk * 32);

  for (int c = 0; c < nt; ++c) {
    const int kv0 = c * 64;
    // QK^T: scores 16q x 64kv (A=Q row=lo=q, B=K^T col=lo=kv)
    f32x4 sc[4];
#pragma unroll
    for (int kf = 0; kf < 4; kf++) sc[kf] = (f32x4){0.f, 0.f, 0.f, 0.f};
    __builtin_amdgcn_s_setprio(1);
#pragma unroll
    for (int kf = 0; kf < 4; kf++)
#pragma unroll
      for (int kk = 0; kk < 2; kk++)
        sc[kf] = __builtin_amdgcn_mfma_f32_16x16x32_bf16(qf[kk], kcur[kf][kk], sc[kf], 0, 0, 0);
    __builtin_amdgcn_s_setprio(0);
    // prefetch next chunk's K into kcur (completes during softmax)
    if (c + 1 < nt) {
      const u16* Kn = Kl + (size_t)(kv0 + 64) * 64;
#pragma unroll
      for (int kf = 0; kf < 4; kf++)
#pragma unroll
        for (int kk = 0; kk < 2; kk++)
          kcur[kf][kk] = *(const short8*)(Kn + kf * 16 * 64 + kk * 32);
    }
    // V loads for this chunk (hide under softmax)
    short8 vb[4][2];
#pragma unroll
    for (int nf = 0; nf < 4; nf++)
#pragma unroll
      for (int kk = 0; kk < 2; kk++)
        vb[nf][kk] = *(const short8*)(Vl + (size_t)nf * 16 * SEQ + kv0 + kk * 32);

    if (kv0 + 63 > q0) {  // straddling chunk: causal mask
#pragma unroll
      for (int kf = 0; kf < 4; kf++) {
        int kv = kv0 + kf * 16 + lo;
#pragma unroll
        for (int r = 0; r < 4; r++) {
          int q = q0 + hi * 4 + r;
          if (kv > q) sc[kf][r] = -__builtin_inff();
        }
      }
    }
    // online softmax in exp2 domain (scores pre-scaled by log2e)
    float cm[4], rs[4], corr[4];
#pragma unroll
    for (int r = 0; r < 4; r++)
      cm[r] = fmaxf(fmaxf(sc[0][r], sc[1][r]), fmaxf(sc[2][r], sc[3][r]));
#pragma unroll
    for (int x = 1; x < 16; x <<= 1)
#pragma unroll
      for (int r = 0; r < 4; r++) cm[r] = fmaxf(cm[r], __shfl_xor(cm[r], x, 64));
#pragma unroll
    for (int r = 0; r < 4; r++) {
      float mn = fmaxf(m[r], cm[r]);
      corr[r] = exp2f(m[r] - mn);
      m[r] = mn;
      rs[r] = 0.f;
    }
#pragma unroll
    for (int kf = 0; kf < 4; kf++)
#pragma unroll
      for (int r = 0; r < 4; r++) {
        float p = exp2f(sc[kf][r] - m[r]);
        rs[r] += p;
        Pw[hi * 4 + r][kf * 16 + lo] = f2b(p);  // C-layout -> LDS
      }
#pragma unroll
    for (int x = 1; x < 16; x <<= 1)
#pragma unroll
      for (int r = 0; r < 4; r++) rs[r] += __shfl_xor(rs[r], x, 64);
#pragma unroll
    for (int r = 0; r < 4; r++) ls[r] = ls[r] * corr[r] + rs[r];
#pragma unroll
    for (int nf = 0; nf < 4; nf++) {
      o[nf][0] *= corr[0]; o[nf][1] *= corr[1]; o[nf][2] *= corr[2]; o[nf][3] *= corr[3];
    }
    // PV: A=P (row=lo=q, k=kv from LDS), B=V (col=lo->d via Vt rows, k=kv contiguous)
    short8 pa[2];
#pragma unroll
    for (int kk = 0; kk < 2; kk++)
      pa[kk] = *(const short8*)(&Pw[lo][kk * 32 + hi * 8]);
    __builtin_amdgcn_s_setprio(1);
#pragma unroll
    for (int nf = 0; nf < 4; nf++)
#pragma unroll
      for (int kk = 0; kk < 2; kk++)
        o[nf] = __builtin_amdgcn_mfma_f32_16x16x32_bf16(pa[kk], vb[nf][kk], o[nf], 0, 0, 0);
    __builtin_amdgcn_s_setprio(0);
  }
#pragma unroll
  for (int r = 0; r < 4; r++) ls[r] = 1.0f / ls[r];
#pragma unroll
  for (int nf = 0; nf < 4; nf++)
#pragma unroll
    for (int r = 0; r < 4; r++) {
      int q = q0 + hi * 4 + r;
      int d = nf * 16 + lo;
      AO[((size_t)(b * SEQ + q) * NHEADS + h) * 64 + d] = f2b(o[nf][r] * ls[r]);
    }
}

extern "C" void kernel_launch(void* const* d_in, const int* in_sizes, int n_in,
                              void* d_out, int out_size, void* d_ws, size_t ws_size,
                              hipStream_t stream) {
  const float* query = (const float*)d_in[0];
  const float* key_ = (const float*)d_in[1];
  const float* value = (const float*)d_in[2];
  const float* fcos = (const float*)d_in[3];
  const float* fsin = (const float*)d_in[4];
  const float* wq = (const float*)d_in[5];
  const float* wk = (const float*)d_in[6];
  const float* wv = (const float*)d_in[7];
  const float* wo = (const float*)d_in[8];

  char* ws = (char*)d_ws;
  size_t off = 0;
  auto alloc = [&](size_t elems) {
    u16* p = (u16*)(ws + off);
    off = (off + elems * 2 + 255) & ~(size_t)255;
    return p;
  };
  u16* qf = alloc((size_t)MTOK * DM);
  u16* kf = alloc((size_t)MTOK * DM);
  u16* vf = alloc((size_t)MTOK * DM);
  u16* wqf = alloc((size_t)DM * DM);
  u16* wkf = alloc((size_t)256 * DM);
  u16* wvf = alloc((size_t)256 * DM);
  u16* wof = alloc((size_t)DM * DM);
  u16* Qr = alloc((size_t)MTOK * DM);            // (b,h,s,d)
  u16* Kr = alloc((size_t)NB * NKVH * SEQ * 64); // (b,kh,s,d)
  u16* Vp = alloc((size_t)NB * NKVH * SEQ * 64); // (b,kh,s,d)
  u16* Vt = alloc((size_t)NB * NKVH * 64 * SEQ); // (b,kh,d,s)
  u16* AO = alloc((size_t)MTOK * DM);            // (b,s,h,d)

  cvt3_kernel<<<dim3((MTOK * DM) / 2048, 3), 256, 0, stream>>>(query, key_, value, qf, kf, vf);
  cvtw_kernel<<<(2 * DM * DM + 2 * 256 * DM) / 2048, 256, 0, stream>>>(wq, wk, wv, wo, wqf, wkf, wvf, wof);

  gemm_bt<1, NHEADS><<<dim3(DM / 128, MTOK / 128), 256, 0, stream>>>(qf, wqf, Qr, MTOK, DM, DM);
  gemm_bt<1, NKVH><<<dim3(2, MTOK / 128), 256, 0, stream>>>(kf, wkf, Kr, MTOK, 256, DM);
  gemm_bt<1, NKVH><<<dim3(2, MTOK / 128), 256, 0, stream>>>(vf, wvf, Vp, MTOK, 256, DM);

  rope_kernel<true><<<(NB * NHEADS * SEQ * 8) / 256, 256, 0, stream>>>(Qr, fcos, fsin);
  rope_kernel<false><<<(NB * NKVH * SEQ * 8) / 256, 256, 0, stream>>>(Kr, fcos, fsin);

  transpose_v<<<NB * NKVH * (SEQ / 64), 256, 0, stream>>>(Vp, Vt);

  attn_kernel<<<dim3(NB * NHEADS, SEQ / 64), 256, 0, stream>>>(Qr, Kr, Vt, AO);

  gemm_bt<0, 0><<<dim3(DM / 128, MTOK / 128), 256, 0, stream>>>(AO, wof, d_out, MTOK, DM, DM);
}

// Round 3
// 177.759 us; speedup vs baseline: 1.9956x; 1.5651x over previous
//
#include <hip/hip_runtime.h>

#define DM 1024
#define NHEADS 16
#define NKVH 4
#define HDIM 64
#define NB 2
#define SEQ 2048
#define MTOK (NB*SEQ)

typedef __attribute__((ext_vector_type(4))) float f32x4;
typedef __attribute__((ext_vector_type(8))) short short8;
typedef unsigned short u16;
typedef unsigned int u32;

__device__ __forceinline__ float b2f(u16 u) {
  u32 i = ((u32)u) << 16; float f; __builtin_memcpy(&f, &i, 4); return f;
}
__device__ __forceinline__ u16 f2b(float f) {
  u32 i; __builtin_memcpy(&i, &f, 4);
  u32 r = i + 0x7fffu + ((i >> 16) & 1u);
  return (u16)(r >> 16);
}
__device__ __forceinline__ void gload16(const void* g, void* l) {
  __builtin_amdgcn_global_load_lds((const __attribute__((address_space(1))) u32*)g,
                                   (__attribute__((address_space(3))) u32*)l, 16, 0, 0);
}

// ---------------- fp32 -> bf16 convert ----------------
__device__ __forceinline__ void cvt8(const float* __restrict__ src, u16* __restrict__ dst, int i) {
  float4 a = *(const float4*)(src + i);
  float4 b = *(const float4*)(src + i + 4);
  uint4 pk;
  pk.x = (u32)f2b(a.x) | ((u32)f2b(a.y) << 16);
  pk.y = (u32)f2b(a.z) | ((u32)f2b(a.w) << 16);
  pk.z = (u32)f2b(b.x) | ((u32)f2b(b.y) << 16);
  pk.w = (u32)f2b(b.z) | ((u32)f2b(b.w) << 16);
  *(uint4*)(dst + i) = pk;
}

__global__ __launch_bounds__(256) void cvt3_kernel(const float* __restrict__ a, const float* __restrict__ b,
                                                   const float* __restrict__ c, u16* __restrict__ oa,
                                                   u16* __restrict__ ob, u16* __restrict__ oc) {
  int i = (blockIdx.x * 256 + threadIdx.x) * 8;
  const float* s = (blockIdx.y == 0) ? a : (blockIdx.y == 1) ? b : c;
  u16* d = (blockIdx.y == 0) ? oa : (blockIdx.y == 1) ? ob : oc;
  cvt8(s, d, i);
}

__global__ __launch_bounds__(256) void cvtw_kernel(const float* __restrict__ wq, const float* __restrict__ wk,
                                                   const float* __restrict__ wv, const float* __restrict__ wo,
                                                   u16* __restrict__ oq, u16* __restrict__ ok,
                                                   u16* __restrict__ ov, u16* __restrict__ oo) {
  const int BIG = (DM * DM) / 2048;   // 512 blocks
  const int SML = (256 * DM) / 2048;  // 128 blocks
  int bid = blockIdx.x;
  const float* s; u16* d;
  if (bid < BIG) { s = wq; d = oq; }
  else if (bid < 2 * BIG) { s = wo; d = oo; bid -= BIG; }
  else if (bid < 2 * BIG + SML) { s = wk; d = ok; bid -= 2 * BIG; }
  else { s = wv; d = ov; bid -= 2 * BIG + SML; }
  cvt8(s, d, (bid * 256 + threadIdx.x) * 8);
}

// ---------------- GEMM: C[M,N] = A[M,K] @ W[N,K]^T (bf16 in, MFMA) ----------------
template<int MODE, int OH>
__global__ __launch_bounds__(256) void gemm_bt(const u16* __restrict__ A, const u16* __restrict__ W,
                                               void* __restrict__ Out, int M, int N, int K) {
  __shared__ __attribute__((aligned(16))) u16 As[128 * 64];
  __shared__ __attribute__((aligned(16))) u16 Bs[128 * 64];
  const int tid = threadIdx.x;
  const int lane = tid & 63, w = tid >> 6;
  const int wr = w >> 1, wc = w & 1;
  const int lo = lane & 15, hi = lane >> 4;
  const int m0 = blockIdx.y * 128, n0 = blockIdx.x * 128;

  f32x4 acc[4][4];
#pragma unroll
  for (int i = 0; i < 4; i++)
#pragma unroll
    for (int j = 0; j < 4; j++) acc[i][j] = (f32x4){0.f, 0.f, 0.f, 0.f};

  const int crow = lane >> 3;       // 0..7
  const int ccol = (lane & 7) * 8;  // 0..56

  for (int k0 = 0; k0 < K; k0 += 64) {
#pragma unroll
    for (int cc = 0; cc < 4; ++cc) {
      int c = w * 4 + cc;
      gload16(A + (size_t)(m0 + c * 8 + crow) * K + k0 + ccol, &As[c * 512]);
      gload16(W + (size_t)(n0 + c * 8 + crow) * K + k0 + ccol, &Bs[c * 512]);
    }
    __syncthreads();
    short8 af[4][2], bfr[4][2];
#pragma unroll
    for (int mi = 0; mi < 4; mi++)
#pragma unroll
      for (int kk = 0; kk < 2; kk++)
        af[mi][kk] = *(const short8*)(&As[(wr * 64 + mi * 16 + lo) * 64 + kk * 32 + hi * 8]);
#pragma unroll
    for (int ni = 0; ni < 4; ni++)
#pragma unroll
      for (int kk = 0; kk < 2; kk++)
        bfr[ni][kk] = *(const short8*)(&Bs[(wc * 64 + ni * 16 + lo) * 64 + kk * 32 + hi * 8]);
    __builtin_amdgcn_s_setprio(1);
#pragma unroll
    for (int mi = 0; mi < 4; mi++)
#pragma unroll
      for (int ni = 0; ni < 4; ni++) {
        acc[mi][ni] = __builtin_amdgcn_mfma_f32_16x16x32_bf16(af[mi][0], bfr[ni][0], acc[mi][ni], 0, 0, 0);
        acc[mi][ni] = __builtin_amdgcn_mfma_f32_16x16x32_bf16(af[mi][1], bfr[ni][1], acc[mi][ni], 0, 0, 0);
      }
    __builtin_amdgcn_s_setprio(0);
    __syncthreads();
  }

#pragma unroll
  for (int mi = 0; mi < 4; mi++)
#pragma unroll
    for (int ni = 0; ni < 4; ni++)
#pragma unroll
      for (int r = 0; r < 4; r++) {
        int row = m0 + wr * 64 + mi * 16 + hi * 4 + r;
        int col = n0 + wc * 64 + ni * 16 + lo;
        if (MODE == 0) {
          ((float*)Out)[(size_t)row * N + col] = acc[mi][ni][r];
        } else {
          int b = row >> 11, s = row & (SEQ - 1);
          int h = col >> 6, d = col & 63;
          ((u16*)Out)[((size_t)(b * OH + h) * SEQ + s) * 64 + d] = f2b(acc[mi][ni][r]);
        }
      }
}

// ---------------- RoPE (in-place). SCALE folds ATTN_SCALE*log2(e) into Q ----------------
template<bool SCALE>
__global__ __launch_bounds__(256) void rope_kernel(u16* __restrict__ buf,
                                                   const float* __restrict__ cosb,
                                                   const float* __restrict__ sinb) {
  int idx = blockIdx.x * 256 + threadIdx.x;
  int d0 = (idx & 7) * 8;
  int s = (idx >> 3) & (SEQ - 1);
  u16* p = buf + (size_t)(idx >> 3) * 64 + d0;
  uint4 raw = *(const uint4*)p;
  u32 rw[4] = {raw.x, raw.y, raw.z, raw.w};
  float4 cv = *(const float4*)(cosb + s * 32 + (d0 >> 1));
  float4 sv = *(const float4*)(sinb + s * 32 + (d0 >> 1));
  float ca[4] = {cv.x, cv.y, cv.z, cv.w};
  float sa[4] = {sv.x, sv.y, sv.z, sv.w};
  u32 out[4];
#pragma unroll
  for (int t = 0; t < 4; t++) {
    float xr = b2f((u16)(rw[t] & 0xffff));
    float xi = b2f((u16)(rw[t] >> 16));
    float orr = xr * ca[t] - xi * sa[t];
    float oii = xr * sa[t] + xi * ca[t];
    if (SCALE) { orr *= 0.18033688f; oii *= 0.18033688f; }  // (1/8) * log2(e)
    out[t] = (u32)f2b(orr) | ((u32)f2b(oii) << 16);
  }
  uint4 ov; ov.x = out[0]; ov.y = out[1]; ov.z = out[2]; ov.w = out[3];
  *(uint4*)p = ov;
}

// ---------------- V transpose: (b,kh,s,d) -> (b,kh,d,s) ----------------
__global__ __launch_bounds__(256) void transpose_v(const u16* __restrict__ Vp, u16* __restrict__ Vt) {
  __shared__ __attribute__((aligned(16))) u16 T[64][68];
  int bkh = blockIdx.x >> 5;
  int st = blockIdx.x & 31;
  int t = threadIdx.x;
#pragma unroll
  for (int g = 0; g < 2; ++g) {
    int lin = g * 2048 + t * 8;
    int sr = lin >> 6;
    int dc = lin & 63;
    uint4 v = *(const uint4*)(Vp + ((size_t)bkh * SEQ + st * 64 + sr) * 64 + dc);
    u32 vv[4] = {v.x, v.y, v.z, v.w};
#pragma unroll
    for (int jj = 0; jj < 4; jj++) {
      T[dc + 2 * jj][sr] = (u16)(vv[jj] & 0xffff);
      T[dc + 2 * jj + 1][sr] = (u16)(vv[jj] >> 16);
    }
  }
  __syncthreads();
#pragma unroll
  for (int g = 0; g < 2; ++g) {
    int lin = g * 2048 + t * 8;
    int dr = lin >> 6;
    int sc2 = lin & 63;
    u32 ov[4];
#pragma unroll
    for (int jj = 0; jj < 4; jj++)
      ov[jj] = (u32)T[dr][sc2 + 2 * jj] | ((u32)T[dr][sc2 + 2 * jj + 1] << 16);
    uint4 q4; q4.x = ov[0]; q4.y = ov[1]; q4.z = ov[2]; q4.w = ov[3];
    *(uint4*)(Vt + ((size_t)bkh * 64 + dr) * SEQ + st * 64 + sc2) = q4;
  }
}

// ---------------- Flash attention (causal, GQA). Q pre-scaled by ATTN_SCALE*log2e ----------------
// K,V staged in LDS (shared by 4 waves), double-buffered, source-swizzled for
// conflict-free ds_read.  Defer-max softmax (THR=8) + per-lane partial row-sum.
__global__ __launch_bounds__(256, 3) void attn_kernel(const u16* __restrict__ Q, const u16* __restrict__ Kb,
                                                      const u16* __restrict__ Vt, u16* __restrict__ AO) {
  __shared__ __attribute__((aligned(16))) u16 Ks[2][4096];  // [kv 64][d 64] swizzled
  __shared__ __attribute__((aligned(16))) u16 Vs[2][4096];  // [d 64][kv 64] swizzled
  __shared__ __attribute__((aligned(16))) u16 P[4][16][72]; // per-wave P tile
  const int tid = threadIdx.x;
  const int w = tid >> 6, lane = tid & 63;
  const int lo = lane & 15, hi = lane >> 4;
  const int bh = blockIdx.x;
  const int b = bh >> 4, h = bh & 15, kh = h >> 2;
  const int y = blockIdx.y, y0 = y & 7, gq = y >> 3;
  const int tile = (gq == 0) ? y0 : (gq == 1) ? (15 - y0) : (gq == 2) ? (16 + y0) : (31 - y0);
  const int q0 = tile * 64 + w * 16;
  const u16* Qp = Q + (size_t)bh * SEQ * 64;
  const u16* Kp = Kb + (size_t)(b * NKVH + kh) * SEQ * 64;
  const u16* Vp = Vt + (size_t)(b * NKVH + kh) * 64 * SEQ;

  short8 qf[2];
#pragma unroll
  for (int kk = 0; kk < 2; kk++)
    qf[kk] = *(const short8*)(Qp + (size_t)(q0 + lo) * 64 + kk * 32 + hi * 8);

  f32x4 o[4];
#pragma unroll
  for (int nf = 0; nf < 4; nf++) o[nf] = (f32x4){0.f, 0.f, 0.f, 0.f};
  float m[4], lsp[4];
#pragma unroll
  for (int r = 0; r < 4; r++) { m[r] = -__builtin_inff(); lsp[r] = 0.f; }

  u16 (*Pw)[72] = P[w];

  // stage one 64-kv chunk of K and V into LDS buf (linear dest, swizzled source)
  auto stage = [&](int kv0, int bufi) {
#pragma unroll
    for (int s = 0; s < 2; s++) {
      int base = s * 4096 + w * 1024;   // bytes, wave-uniform
      int o2 = base + (lane << 4);      // this lane's dest byte
      int row = o2 >> 7;
      int gg = ((o2 >> 4) & 7) ^ (row & 7);
      gload16(Kp + (size_t)(kv0 + row) * 64 + gg * 8, (char*)&Ks[bufi][0] + base);
      gload16(Vp + (size_t)row * SEQ + kv0 + gg * 8, (char*)&Vs[bufi][0] + base);
    }
  };
  // swizzled ds_read of one 8-elem group
  auto lds8 = [&](const u16* S, int row, int col8) {
    return *(const short8*)(S + row * 64 + (col8 ^ ((row & 7) << 3)));
  };

  const int nt = tile + 1;
  stage(0, 0);
  __syncthreads();

  for (int c = 0; c < nt; ++c) {
    const int cur = c & 1;
    const int kv0 = c * 64;
    if (c + 1 < nt) stage(kv0 + 64, cur ^ 1);

    short8 kb2[4][2], vb[4][2];
#pragma unroll
    for (int kf = 0; kf < 4; kf++)
#pragma unroll
      for (int kk = 0; kk < 2; kk++)
        kb2[kf][kk] = lds8(&Ks[cur][0], kf * 16 + lo, kk * 32 + hi * 8);
#pragma unroll
    for (int nf = 0; nf < 4; nf++)
#pragma unroll
      for (int kk = 0; kk < 2; kk++)
        vb[nf][kk] = lds8(&Vs[cur][0], nf * 16 + lo, kk * 32 + hi * 8);

    f32x4 sc[4];
#pragma unroll
    for (int kf = 0; kf < 4; kf++) sc[kf] = (f32x4){0.f, 0.f, 0.f, 0.f};
    __builtin_amdgcn_s_setprio(1);
#pragma unroll
    for (int kf = 0; kf < 4; kf++)
#pragma unroll
      for (int kk = 0; kk < 2; kk++)
        sc[kf] = __builtin_amdgcn_mfma_f32_16x16x32_bf16(qf[kk], kb2[kf][kk], sc[kf], 0, 0, 0);
    __builtin_amdgcn_s_setprio(0);

    if (kv0 + 63 > q0) {  // straddling chunk: causal mask
#pragma unroll
      for (int kf = 0; kf < 4; kf++) {
        int kv = kv0 + kf * 16 + lo;
#pragma unroll
        for (int r = 0; r < 4; r++) {
          int q = q0 + hi * 4 + r;
          if (kv > q) sc[kf][r] = -__builtin_inff();
        }
      }
    }

    // defer-max online softmax (exp2 domain; scores pre-scaled by log2e)
    float lm[4];
#pragma unroll
    for (int r = 0; r < 4; r++)
      lm[r] = fmaxf(fmaxf(sc[0][r], sc[1][r]), fmaxf(sc[2][r], sc[3][r]));
    float dmax = fmaxf(fmaxf(lm[0] - m[0], lm[1] - m[1]), fmaxf(lm[2] - m[2], lm[3] - m[3]));
    if (__any(dmax > 8.f)) {  // rare: full max reduce + rescale
      float cm[4];
#pragma unroll
      for (int r = 0; r < 4; r++) cm[r] = fmaxf(m[r], lm[r]);
#pragma unroll
      for (int x = 1; x < 16; x <<= 1)
#pragma unroll
        for (int r = 0; r < 4; r++) cm[r] = fmaxf(cm[r], __shfl_xor(cm[r], x, 64));
      float corr[4];
#pragma unroll
      for (int r = 0; r < 4; r++) {
        corr[r] = exp2f(m[r] - cm[r]);
        m[r] = cm[r];
        lsp[r] *= corr[r];
      }
#pragma unroll
      for (int nf = 0; nf < 4; nf++) {
        o[nf][0] *= corr[0]; o[nf][1] *= corr[1]; o[nf][2] *= corr[2]; o[nf][3] *= corr[3];
      }
    }
#pragma unroll
    for (int kf = 0; kf < 4; kf++)
#pragma unroll
      for (int r = 0; r < 4; r++) {
        float p = exp2f(sc[kf][r] - m[r]);
        lsp[r] += p;
        Pw[hi * 4 + r][kf * 16 + lo] = f2b(p);
      }

    short8 pa[2];
#pragma unroll
    for (int kk = 0; kk < 2; kk++)
      pa[kk] = *(const short8*)(&Pw[lo][kk * 32 + hi * 8]);
    __builtin_amdgcn_s_setprio(1);
#pragma unroll
    for (int nf = 0; nf < 4; nf++)
#pragma unroll
      for (int kk = 0; kk < 2; kk++)
        o[nf] = __builtin_amdgcn_mfma_f32_16x16x32_bf16(pa[kk], vb[nf][kk], o[nf], 0, 0, 0);
    __builtin_amdgcn_s_setprio(0);
    __syncthreads();
  }

  // final row-sum reduce (once, not per chunk)
#pragma unroll
  for (int x = 1; x < 16; x <<= 1)
#pragma unroll
    for (int r = 0; r < 4; r++) lsp[r] += __shfl_xor(lsp[r], x, 64);
  float inv[4];
#pragma unroll
  for (int r = 0; r < 4; r++) inv[r] = 1.0f / lsp[r];
#pragma unroll
  for (int nf = 0; nf < 4; nf++)
#pragma unroll
    for (int r = 0; r < 4; r++) {
      int q = q0 + hi * 4 + r;
      int d = nf * 16 + lo;
      AO[((size_t)(b * SEQ + q) * NHEADS + h) * 64 + d] = f2b(o[nf][r] * inv[r]);
    }
}

extern "C" void kernel_launch(void* const* d_in, const int* in_sizes, int n_in,
                              void* d_out, int out_size, void* d_ws, size_t ws_size,
                              hipStream_t stream) {
  const float* query = (const float*)d_in[0];
  const float* key_ = (const float*)d_in[1];
  const float* value = (const float*)d_in[2];
  const float* fcos = (const float*)d_in[3];
  const float* fsin = (const float*)d_in[4];
  const float* wq = (const float*)d_in[5];
  const float* wk = (const float*)d_in[6];
  const float* wv = (const float*)d_in[7];
  const float* wo = (const float*)d_in[8];

  char* ws = (char*)d_ws;
  size_t off = 0;
  auto alloc = [&](size_t elems) {
    u16* p = (u16*)(ws + off);
    off = (off + elems * 2 + 255) & ~(size_t)255;
    return p;
  };
  u16* qf = alloc((size_t)MTOK * DM);
  u16* kf = alloc((size_t)MTOK * DM);
  u16* vf = alloc((size_t)MTOK * DM);
  u16* wqf = alloc((size_t)DM * DM);
  u16* wkf = alloc((size_t)256 * DM);
  u16* wvf = alloc((size_t)256 * DM);
  u16* wof = alloc((size_t)DM * DM);
  u16* Qr = alloc((size_t)MTOK * DM);            // (b,h,s,d)
  u16* Kr = alloc((size_t)NB * NKVH * SEQ * 64); // (b,kh,s,d)
  u16* Vp = alloc((size_t)NB * NKVH * SEQ * 64); // (b,kh,s,d)
  u16* Vt = alloc((size_t)NB * NKVH * 64 * SEQ); // (b,kh,d,s)
  u16* AO = alloc((size_t)MTOK * DM);            // (b,s,h,d)

  cvt3_kernel<<<dim3((MTOK * DM) / 2048, 3), 256, 0, stream>>>(query, key_, value, qf, kf, vf);
  cvtw_kernel<<<(2 * DM * DM + 2 * 256 * DM) / 2048, 256, 0, stream>>>(wq, wk, wv, wo, wqf, wkf, wvf, wof);

  gemm_bt<1, NHEADS><<<dim3(DM / 128, MTOK / 128), 256, 0, stream>>>(qf, wqf, Qr, MTOK, DM, DM);
  gemm_bt<1, NKVH><<<dim3(2, MTOK / 128), 256, 0, stream>>>(kf, wkf, Kr, MTOK, 256, DM);
  gemm_bt<1, NKVH><<<dim3(2, MTOK / 128), 256, 0, stream>>>(vf, wvf, Vp, MTOK, 256, DM);

  rope_kernel<true><<<(NB * NHEADS * SEQ * 8) / 256, 256, 0, stream>>>(Qr, fcos, fsin);
  rope_kernel<false><<<(NB * NKVH * SEQ * 8) / 256, 256, 0, stream>>>(Kr, fcos, fsin);

  transpose_v<<<NB * NKVH * (SEQ / 64), 256, 0, stream>>>(Vp, Vt);

  attn_kernel<<<dim3(NB * NHEADS, SEQ / 64), 256, 0, stream>>>(Qr, Kr, Vt, AO);

  gemm_bt<0, 0><<<dim3(DM / 128, MTOK / 128), 256, 0, stream>>>(AO, wof, d_out, MTOK, DM, DM);
}

// Round 4
// 144.483 us; speedup vs baseline: 2.4552x; 1.2303x over previous
//
#include <hip/hip_runtime.h>

#define DM 1024
#define NHEADS 16
#define NKVH 4
#define HDIM 64
#define NB 2
#define SEQ 2048
#define MTOK (NB*SEQ)

typedef __attribute__((ext_vector_type(4))) float f32x4;
typedef __attribute__((ext_vector_type(8))) short short8;
typedef unsigned short u16;
typedef unsigned int u32;

__device__ __forceinline__ float b2f(u16 u) {
  u32 i = ((u32)u) << 16; float f; __builtin_memcpy(&f, &i, 4); return f;
}
__device__ __forceinline__ u16 f2b(float f) {
  u32 i; __builtin_memcpy(&i, &f, 4);
  u32 r = i + 0x7fffu + ((i >> 16) & 1u);
  return (u16)(r >> 16);
}
__device__ __forceinline__ u32 cvtpk(float a, float b) {  // low16=bf16(a), high16=bf16(b)
  u32 r; asm("v_cvt_pk_bf16_f32 %0, %1, %2" : "=v"(r) : "v"(a), "v"(b)); return r;
}
__device__ __forceinline__ void gload16(const void* g, void* l) {
  __builtin_amdgcn_global_lo\
ad_lds((const __attribute__((address_space(1))) u32*)g,
                                   (__attribute__((address_space(3))) u32*)l, 16, 0, 0);
}

// ---------------- fused fp32 -> bf16 convert (all 7 tensors, one launch) ----------------
__device__ __forceinline__ void cvt8(const float* __restrict__ src, u16* __restrict__ dst, int i) {
  float4 a = *(const float4*)(src + i);
  float4 b = *(const float4*)(src + i + 4);
  uint4 pk;
  pk.x = (u32)f2b(a.x) | ((u32)f2b(a.y) << 16);
  pk.y = (u32)f2b(a.z) | ((u32)f2b(a.w) << 16);
  pk.z = (u32)f2b(b.x) | ((u32)f2b(b.y) << 16);
  pk.w = (u32)f2b(b.z) | ((u32)f2b(b.w) << 16);
  *(uint4*)(dst + i) = pk;
}

__global__ __launch_bounds__(256) void cvt_all(const float* __restrict__ q, const float* __restrict__ k,
                                               const float* __restrict__ v, const float* __restrict__ wq,
                                               const float* __restrict__ wk, const float* __restrict__ wv,
                                               const float* __restrict__ wo, u16* oq, u16* ok, u16* ov,
                                               u16* owq, u16* owk, u16* owv, u16* owo) {
  const int ACT = (MTOK * DM) / 2048;  // 2048 blocks per activation tensor
  const int BIG = (DM * DM) / 2048;    // 512
  const int SML = (256 * DM) / 2048;   // 128
  int bid = blockIdx.x;
  const float* s; u16* d;
  if (bid < ACT) { s = q; d = oq; }
  else if (bid < 2 * ACT) { s = k; d = ok; bid -= ACT; }
  else if (bid < 3 * ACT) { s = v; d = ov; bid -= 2 * ACT; }
  else {
    bid -= 3 * ACT;
    if (bid < BIG) { s = wq; d = owq; }
    else if (bid < 2 * BIG) { s = wo; d = owo; bid -= BIG; }
    else if (bid < 2 * BIG + SML) { s = wk; d = owk; bid -= 2 * BIG; }
    else { s = wv; d = owv; bid -= 2 * BIG + SML; }
  }
  cvt8(s, d, (bid * 256 + threadIdx.x) * 8);
}

// ---------------- GEMM body: C[M,N] = A[M,K] @ W[N,K]^T ----------------
template<int MODE, int OH>
__device__ __forceinline__ void gemm_body(u16* As, u16* Bs, const u16* __restrict__ A,
                                          const u16* __restrict__ W, void* __restrict__ Out,
                                          int M, int N, int K, int bx, int by) {
  const int tid = threadIdx.x;
  const int lane = tid & 63, w = tid >> 6;
  const int wr = w >> 1, wc = w & 1;
  const int lo = lane & 15, hi = lane >> 4;
  const int m0 = by * 128, n0 = bx * 128;

  f32x4 acc[4][4];
#pragma unroll
  for (int i = 0; i < 4; i++)
#pragma unroll
    for (int j = 0; j < 4; j++) acc[i][j] = (f32x4){0.f, 0.f, 0.f, 0.f};

  const int crow = lane >> 3;
  const int ccol = (lane & 7) * 8;

  for (int k0 = 0; k0 < K; k0 += 64) {
#pragma unroll
    for (int cc = 0; cc < 4; ++cc) {
      int c = w * 4 + cc;
      gload16(A + (size_t)(m0 + c * 8 + crow) * K + k0 + ccol, &As[c * 512]);
      gload16(W + (size_t)(n0 + c * 8 + crow) * K + k0 + ccol, &Bs[c * 512]);
    }
    __syncthreads();
    short8 af[4][2], bfr[4][2];
#pragma unroll
    for (int mi = 0; mi < 4; mi++)
#pragma unroll
      for (int kk = 0; kk < 2; kk++)
        af[mi][kk] = *(const short8*)(&As[(wr * 64 + mi * 16 + lo) * 64 + kk * 32 + hi * 8]);
#pragma unroll
    for (int ni = 0; ni < 4; ni++)
#pragma unroll
      for (int kk = 0; kk < 2; kk++)
        bfr[ni][kk] = *(const short8*)(&Bs[(wc * 64 + ni * 16 + lo) * 64 + kk * 32 + hi * 8]);
    __builtin_amdgcn_s_setprio(1);
#pragma unroll
    for (int mi = 0; mi < 4; mi++)
#pragma unroll
      for (int ni = 0; ni < 4; ni++) {
        acc[mi][ni] = __builtin_amdgcn_mfma_f32_16x16x32_bf16(af[mi][0], bfr[ni][0], acc[mi][ni], 0, 0, 0);
        acc[mi][ni] = __builtin_amdgcn_mfma_f32_16x16x32_bf16(af[mi][1], bfr[ni][1], acc[mi][ni], 0, 0, 0);
      }
    __builtin_amdgcn_s_setprio(0);
    __syncthreads();
  }

#pragma unroll
  for (int mi = 0; mi < 4; mi++)
#pragma unroll
    for (int ni = 0; ni < 4; ni++)
#pragma unroll
      for (int r = 0; r < 4; r++) {
        int row = m0 + wr * 64 + mi * 16 + hi * 4 + r;
        int col = n0 + wc * 64 + ni * 16 + lo;
        if (MODE == 0) {
          ((float*)Out)[(size_t)row * N + col] = acc[mi][ni][r];
        } else {
          int b = row >> 11, s = row & (SEQ - 1);
          int h = col >> 6, d = col & 63;
          ((u16*)Out)[((size_t)(b * OH + h) * SEQ + s) * 64 + d] = f2b(acc[mi][ni][r]);
        }
      }
}

template<int MODE, int OH>
__global__ __launch_bounds__(256) void gemm_bt(const u16* __restrict__ A, const u16* __restrict__ W,
                                               void* __restrict__ Out, int M, int N, int K) {
  __shared__ __attribute__((aligned(16))) u16 As[128 * 64];
  __shared__ __attribute__((aligned(16))) u16 Bs[128 * 64];
  gemm_body<MODE, OH>(As, Bs, A, W, Out, M, N, K, blockIdx.x, blockIdx.y);
}

// K-proj and V-proj in one launch (blockIdx.z selects)
__global__ __launch_bounds__(256) void gemm_kv(const u16* __restrict__ A0, const u16* __restrict__ W0,
                                               u16* __restrict__ O0, const u16* __restrict__ A1,
                                               const u16* __restrict__ W1, u16* __restrict__ O1) {
  __shared__ __attribute__((aligned(16))) u16 As[128 * 64];
  __shared__ __attribute__((aligned(16))) u16 Bs[128 * 64];
  if (blockIdx.z == 0)
    gemm_body<1, NKVH>(As, Bs, A0, W0, O0, MTOK, 256, DM, blockIdx.x, blockIdx.y);
  else
    gemm_body<1, NKVH>(As, Bs, A1, W1, O1, MTOK, 256, DM, blockIdx.x, blockIdx.y);
}

// ---------------- fused RoPE for Q (scaled) and K, one launch ----------------
__global__ __launch_bounds__(256) void rope_all(u16* __restrict__ Qb, u16* __restrict__ Kb,
                                                const float* __restrict__ cosb,
                                                const float* __restrict__ sinb) {
  int bid = blockIdx.x;
  u16* buf; float scale;
  if (bid < 2048) { buf = Qb; scale = 0.18033688f; }            // (1/8)*log2(e) folded into Q
  else { buf = Kb; scale = 1.0f; bid -= 2048; }
  int idx = bid * 256 + threadIdx.x;
  int d0 = (idx & 7) * 8;
  int s = (idx >> 3) & (SEQ - 1);
  u16* p = buf + (size_t)(idx >> 3) * 64 + d0;
  uint4 raw = *(const uint4*)p;
  u32 rw[4] = {raw.x, raw.y, raw.z, raw.w};
  float4 cv = *(const float4*)(cosb + s * 32 + (d0 >> 1));
  float4 sv = *(const float4*)(sinb + s * 32 + (d0 >> 1));
  float ca[4] = {cv.x, cv.y, cv.z, cv.w};
  float sa[4] = {sv.x, sv.y, sv.z, sv.w};
  u32 out[4];
#pragma unroll
  for (int t = 0; t < 4; t++) {
    float xr = b2f((u16)(rw[t] & 0xffff));
    float xi = b2f((u16)(rw[t] >> 16));
    float orr = (xr * ca[t] - xi * sa[t]) * scale;
    float oii = (xr * sa[t] + xi * ca[t]) * scale;
    out[t] = (u32)f2b(orr) | ((u32)f2b(oii) << 16);
  }
  uint4 ov; ov.x = out[0]; ov.y = out[1]; ov.z = out[2]; ov.w = out[3];
  *(uint4*)p = ov;
}

// ---------------- V transpose: (b,kh,s,d) -> (b,kh,d,s) ----------------
__global__ __launch_bounds__(256) void transpose_v(const u16* __restrict__ Vp, u16* __restrict__ Vt) {
  __shared__ __attribute__((aligned(16))) u16 T[64][68];
  int bkh = blockIdx.x >> 5;
  int st = blockIdx.x & 31;
  int t = threadIdx.x;
#pragma unroll
  for (int g = 0; g < 2; ++g) {
    int lin = g * 2048 + t * 8;
    int sr = lin >> 6;
    int dc = lin & 63;
    uint4 v = *(const uint4*)(Vp + ((size_t)bkh * SEQ + st * 64 + sr) * 64 + dc);
    u32 vv[4] = {v.x, v.y, v.z, v.w};
#pragma unroll
    for (int jj = 0; jj < 4; jj++) {
      T[dc + 2 * jj][sr] = (u16)(vv[jj] & 0xffff);
      T[dc + 2 * jj + 1][sr] = (u16)(vv[jj] >> 16);
    }
  }
  __syncthreads();
#pragma unroll
  for (int g = 0; g < 2; ++g) {
    int lin = g * 2048 + t * 8;
    int dr = lin >> 6;
    int sc2 = lin & 63;
    u32 ov[4];
#pragma unroll
    for (int jj = 0; jj < 4; jj++)
      ov[jj] = (u32)T[dr][sc2 + 2 * jj] | ((u32)T[dr][sc2 + 2 * jj + 1] << 16);
    uint4 q4; q4.x = ov[0]; q4.y = ov[1]; q4.z = ov[2]; q4.w = ov[3];
    *(uint4*)(Vt + ((size_t)bkh * 64 + dr) * SEQ + st * 64 + sc2) = q4;
  }
}

// ---------------- Flash attention: swapped QK^T, P stays in registers ----------------
// S^T = mfma(K,Q) with kv-slot permutation kappa so each lane holds exactly the
// PV A-fragment kv set {8*hi..8*hi+7} per 32-window for its q=lo row.
__global__ __launch_bounds__(256, 4) void attn_kernel(const u16* __restrict__ Q, const u16* __restrict__ Kb,
                                                      const u16* __restrict__ Vt, u16* __restrict__ AO) {
  __shared__ __attribute__((aligned(16))) u16 Ks[2][4096];  // [kv 64][d 64] swizzled
  __shared__ __attribute__((aligned(16))) u16 Vs[2][4096];  // [d 64][kv 64] swizzled
  const int tid = threadIdx.x;
  const int w = tid >> 6, lane = tid & 63;
  const int lo = lane & 15, hi = lane >> 4;
  const int bh = blockIdx.x;
  const int b = bh >> 4, h = bh & 15, kh = h >> 2;
  const int y = blockIdx.y, y0 = y & 7, gq = y >> 3;
  const int tile = (gq == 0) ? y0 : (gq == 1) ? (15 - y0) : (gq == 2) ? (16 + y0) : (31 - y0);
  const int q0 = tile * 64 + w * 16;
  const u16* Qp = Q + (size_t)bh * SEQ * 64;
  const u16* Kp = Kb + (size_t)(b * NKVH + kh) * SEQ * 64;
  const u16* Vp = Vt + (size_t)(b * NKVH + kh) * 64 * SEQ;

  short8 qf[2];
#pragma unroll
  for (int kk = 0; kk < 2; kk++)
    qf[kk] = *(const short8*)(Qp + (size_t)(q0 + lo) * 64 + kk * 32 + hi * 8);

  f32x4 o[4];
#pragma unroll
  for (int nf = 0; nf < 4; nf++) o[nf] = (f32x4){0.f, 0.f, 0.f, 0.f};
  float m = -__builtin_inff(), lsp = 0.f;

  // swizzle key chosen so both the kappa-pattern K reads and the V reads spread banks
  auto key = [](int row) { return (row & 3) | (((row >> 3) & 1) << 2); };

  auto stage = [&](int kv0, int bufi) {
#pragma unroll
    for (int s = 0; s < 2; s++) {
      int base = s * 4096 + w * 1024;   // byte offset, wave-uniform
      int o2 = base + (lane << 4);
      int row = o2 >> 7;
      int gg = ((o2 >> 4) & 7) ^ key(row);
      gload16(Kp + (size_t)(kv0 + row) * 64 + gg * 8, (char*)&Ks[bufi][0] + base);
      gload16(Vp + (size_t)row * SEQ + kv0 + gg * 8, (char*)&Vs[bufi][0] + base);
    }
  };
  auto lds8 = [&](const u16* S, int row, int col8) {
    return *(const short8*)(S + row * 64 + (col8 ^ (key(row) << 3)));
  };

  // kappa: A-slot (=lo) -> kv row within 64-chunk, for QK^T frag f
  int krow[4];
#pragma unroll
  for (int f = 0; f < 4; f++)
    krow[f] = 32 * (f >> 1) + 8 * (lo >> 2) + 4 * (f & 1) + (lo & 3);

  const int nt = tile + 1;
  stage(0, 0);
  __syncthreads();

  for (int c = 0; c < nt; ++c) {
    const int cur = c & 1;
    const int kv0 = c * 64;
    if (c + 1 < nt) stage(kv0 + 64, cur ^ 1);

    // S^T: sc[f][r] = S[kv = kv0+32*(f>>1)+8*hi+4*(f&1)+r][q = q0+lo]
    f32x4 sc[4];
#pragma unroll
    for (int f = 0; f < 4; f++) sc[f] = (f32x4){0.f, 0.f, 0.f, 0.f};
    __builtin_amdgcn_s_setprio(1);
#pragma unroll
    for (int f = 0; f < 4; f++) {
      short8 kfr0 = lds8(&Ks[cur][0], krow[f], hi * 8);
      short8 kfr1 = lds8(&Ks[cur][0], krow[f], 32 + hi * 8);
      sc[f] = __builtin_amdgcn_mfma_f32_16x16x32_bf16(kfr0, qf[0], sc[f], 0, 0, 0);
      sc[f] = __builtin_amdgcn_mfma_f32_16x16x32_bf16(kfr1, qf[1], sc[f], 0, 0, 0);
    }
    __builtin_amdgcn_s_setprio(0);

    if (kv0 + 63 > q0) {  // straddling chunk: causal mask (kv > q)
#pragma unroll
      for (int f = 0; f < 4; f++) {
        int kvb = kv0 + 32 * (f >> 1) + 8 * hi + 4 * (f & 1);
#pragma unroll
        for (int r = 0; r < 4; r++)
          if (kvb + r > q0 + lo) sc[f][r] = -__builtin_inff();
      }
    }

    // defer-max online softmax (exp2 domain), state per lane for q=lo
    float lm = sc[0][0];
#pragma unroll
    for (int f = 0; f < 4; f++)
#pragma unroll
      for (int r = 0; r < 4; r++) lm = fmaxf(lm, sc[f][r]);
    if (__any(lm - m > 8.f)) {
      float mx = fmaxf(m, lm);
      mx = fmaxf(mx, __shfl_xor(mx, 16, 64));
      mx = fmaxf(mx, __shfl_xor(mx, 32, 64));
      float corr = exp2f(m - mx);
      m = mx;
      lsp *= corr;
      float corrq[4];
#pragma unroll
      for (int r = 0; r < 4; r++) corrq[r] = __shfl(corr, hi * 4 + r, 64);
#pragma unroll
      for (int nf = 0; nf < 4; nf++)
#pragma unroll
        for (int r = 0; r < 4; r++) o[nf][r] *= corrq[r];
    }
    float pv2[4][4];
#pragma unroll
    for (int f = 0; f < 4; f++)
#pragma unroll
      for (int r = 0; r < 4; r++) {
        pv2[f][r] = exp2f(sc[f][r] - m);
        lsp += pv2[f][r];
      }
    // pack P into PV A-fragments: window w2 reg t holds kv pair (32*w2+8*hi+2t, +1)
    union { u32 u[4]; short8 s8; } pa0, pa1;
#pragma unroll
    for (int t = 0; t < 4; t++) {
      int fsel = t >> 1, r0 = 2 * (t & 1);
      pa0.u[t] = cvtpk(pv2[fsel][r0], pv2[fsel][r0 + 1]);
      pa1.u[t] = cvtpk(pv2[2 + fsel][r0], pv2[2 + fsel][r0 + 1]);
    }

    __builtin_amdgcn_s_setprio(1);
#pragma unroll
    for (int nf = 0; nf < 4; nf++) {
      short8 vb0 = lds8(&Vs[cur][0], nf * 16 + lo, hi * 8);
      short8 vb1 = lds8(&Vs[cur][0], nf * 16 + lo, 32 + hi * 8);
      o[nf] = __builtin_amdgcn_mfma_f32_16x16x32_bf16(pa0.s8, vb0, o[nf], 0, 0, 0);
      o[nf] = __builtin_amdgcn_mfma_f32_16x16x32_bf16(pa1.s8, vb1, o[nf], 0, 0, 0);
    }
    __builtin_amdgcn_s_setprio(0);
    __syncthreads();
  }

  // final: reduce row-sum across the 4 hi copies, then distribute 1/lsp to o rows
  lsp += __shfl_xor(lsp, 16, 64);
  lsp += __shfl_xor(lsp, 32, 64);
  float inv = 1.0f / lsp;
  float invq[4];
#pragma unroll
  for (int r = 0; r < 4; r++) invq[r] = __shfl(inv, hi * 4 + r, 64);
#pragma unroll
  for (int nf = 0; nf < 4; nf++)
#pragma unroll
    for (int r = 0; r < 4; r++) {
      int q = q0 + hi * 4 + r;
      int d = nf * 16 + lo;
      AO[((size_t)(b * SEQ + q) * NHEADS + h) * 64 + d] = f2b(o[nf][r] * invq[r]);
    }
}

extern "C" void kernel_launch(void* const* d_in, const int* in_sizes, int n_in,
                              void* d_out, int out_size, void* d_ws, size_t ws_size,
                              hipStream_t stream) {
  const float* query = (const float*)d_in[0];
  const float* key_ = (const float*)d_in[1];
  const float* value = (const float*)d_in[2];
  const float* fcos = (const float*)d_in[3];
  const float* fsin = (const float*)d_in[4];
  const float* wq = (const float*)d_in[5];
  const float* wk = (const float*)d_in[6];
  const float* wv = (const float*)d_in[7];
  const float* wo = (const float*)d_in[8];

  char* ws = (char*)d_ws;
  size_t off = 0;
  auto alloc = [&](size_t elems) {
    u16* p = (u16*)(ws + off);
    off = (off + elems * 2 + 255) & ~(size_t)255;
    return p;
  };
  u16* qf = alloc((size_t)MTOK * DM);
  u16* kf = alloc((size_t)MTOK * DM);
  u16* vf = alloc((size_t)MTOK * DM);
  u16* wqf = alloc((size_t)DM * DM);
  u16* wkf = alloc((size_t)256 * DM);
  u16* wvf = alloc((size_t)256 * DM);
  u16* wof = alloc((size_t)DM * DM);
  u16* Qr = alloc((size_t)MTOK * DM);            // (b,h,s,d)
  u16* Kr = alloc((size_t)NB * NKVH * SEQ * 64); // (b,kh,s,d)
  u16* Vp = alloc((size_t)NB * NKVH * SEQ * 64); // (b,kh,s,d)
  u16* Vt = alloc((size_t)NB * NKVH * 64 * SEQ); // (b,kh,d,s)
  u16* AO = alloc((size_t)MTOK * DM);            // (b,s,h,d)

  cvt_all<<<3 * 2048 + 1280, 256, 0, stream>>>(query, key_, value, wq, wk, wv, wo,
                                               qf, kf, vf, wqf, wkf, wvf, wof);

  gemm_bt<1, NHEADS><<<dim3(DM / 128, MTOK / 128), 256, 0, stream>>>(qf, wqf, Qr, MTOK, DM, DM);
  gemm_kv<<<dim3(2, MTOK / 128, 2), 256, 0, stream>>>(kf, wkf, Kr, vf, wvf, Vp);

  rope_all<<<2048 + 512, 256, 0, stream>>>(Qr, Kr, fcos, fsin);

  transpose_v<<<NB * NKVH * (SEQ / 64), 256, 0, stream>>>(Vp, Vt);

  attn_kernel<<<dim3(NB * NHEADS, SEQ / 64), 256, 0, stream>>>(Qr, Kr, Vt, AO);

  gemm_bt<0, 0><<<dim3(DM / 128, MTOK / 128), 256, 0, stream>>>(AO, wof, d_out, MTOK, DM, DM);
}

// Round 5
// 136.086 us; speedup vs baseline: 2.6067x; 1.0617x over previous
//
#include <hip/hip_runtime.h>

#define DM 1024
#define NHEADS 16
#define NKVH 4
#define HDIM 64
#define NB 2
#define SEQ 2048
#define MTOK (NB*SEQ)

typedef __attribute__((ext_vector_type(4))) float f32x4;
typedef __attribute__((ext_vector_type(8))) short short8;
typedef unsigned short u16;
typedef unsigned int u32;

__device__ __forceinline__ float b2f(u16 u) {
  u32 i = ((u32)u) << 16; float f; __builtin_memcpy(&f, &i, 4); return f;
}
__device__ __forceinline__ u16 f2b(float f) {
  u32 i; __builtin_memcpy(&i, &f, 4);
  u32 r = i + 0x7fffu + ((i >> 16) & 1u);
  return (u16)(r >> 16);
}
__device__ __forceinline__ u32 cvtpk(float a, float b) {  // low16=bf16(a), high16=bf16(b)
  u32 r; asm("v_cvt_pk_bf16_f32 %0, %1, %2" : "=v"(r) : "v"(a), "v"(b)); return r;
}
__device__ __forceinline__ void gload16(const void* g, void* l) {
  __builtin_amdgcn_global_load_lds((const __attribute__((address_space(1))) u32*)g,
                                   (__attribute__((address_space(3))) u32*)l, 16, 0, 0);
}

// ---------------- fused fp32 -> bf16 convert (all 7 tensors, one launch) ----------------
__device__ __forceinline__ void cvt8(const float* __restrict__ src, u16* __restrict__ dst, int i) {
  float4 a = *(const float4*)(src + i);
  float4 b = *(const float4*)(src + i + 4);
  uint4 pk;
  pk.x = (u32)f2b(a.x) | ((u32)f2b(a.y) << 16);
  pk.y = (u32)f2b(a.z) | ((u32)f2b(a.w) << 16);
  pk.z = (u32)f2b(b.x) | ((u32)f2b(b.y) << 16);
  pk.w = (u32)f2b(b.z) | ((u32)f2b(b.w) << 16);
  *(uint4*)(dst + i) = pk;
}

__global__ __launch_bounds__(256) void cvt_all(const float* __restrict__ q, const float* __restrict__ k,
                                               const float* __restrict__ v, const float* __restrict__ wq,
                                               const float* __restrict__ wk, const float* __restrict__ wv,
                                               const float* __restrict__ wo, u16* oq, u16* ok, u16* ov,
                                               u16* owq, u16* owk, u16* owv, u16* owo) {
  const int ACT = (MTOK * DM) / 2048;  // 2048 blocks per activation tensor
  const int BIG = (DM * DM) / 2048;    // 512
  const int SML = (256 * DM) / 2048;   // 128
  int bid = blockIdx.x;
  const float* s; u16* d;
  if (bid < ACT) { s = q; d = oq; }
  else if (bid < 2 * ACT) { s = k; d = ok; bid -= ACT; }
  else if (bid < 3 * ACT) { s = v; d = ov; bid -= 2 * ACT; }
  else {
    bid -= 3 * ACT;
    if (bid < BIG) { s = wq; d = owq; }
    else if (bid < 2 * BIG) { s = wo; d = owo; bid -= BIG; }
    else if (bid < 2 * BIG + SML) { s = wk; d = owk; bid -= 2 * BIG; }
    else { s = wv; d = owv; bid -= 2 * BIG + SML; }
  }
  cvt8(s, d, (bid * 256 + threadIdx.x) * 8);
}

// ---------------- GEMM body: C[M,N] = A[M,K] @ W[N,K]^T ----------------
template<int MODE, int OH>
__device__ __forceinline__ void gemm_body(u16* As, u16* Bs, const u16* __restrict__ A,
                                          const u16* __restrict__ W, void* __restrict__ Out,
                                          int M, int N, int K, int bx, int by) {
  const int tid = threadIdx.x;
  const int lane = tid & 63, w = tid >> 6;
  const int wr = w >> 1, wc = w & 1;
  const int lo = lane & 15, hi = lane >> 4;
  const int m0 = by * 128, n0 = bx * 128;

  f32x4 acc[4][4];
#pragma unroll
  for (int i = 0; i < 4; i++)
#pragma unroll
    for (int j = 0; j < 4; j++) acc[i][j] = (f32x4){0.f, 0.f, 0.f, 0.f};

  const int crow = lane >> 3;
  const int ccol = (lane & 7) * 8;

  for (int k0 = 0; k0 < K; k0 += 64) {
#pragma unroll
    for (int cc = 0; cc < 4; ++cc) {
      int c = w * 4 + cc;
      gload16(A + (size_t)(m0 + c * 8 + crow) * K + k0 + ccol, &As[c * 512]);
      gload16(W + (size_t)(n0 + c * 8 + crow) * K + k0 + ccol, &Bs[c * 512]);
    }
    __syncthreads();
    short8 af[4][2], bfr[4][2];
#pragma unroll
    for (int mi = 0; mi < 4; mi++)
#pragma unroll
      for (int kk = 0; kk < 2; kk++)
        af[mi][kk] = *(const short8*)(&As[(wr * 64 + mi * 16 + lo) * 64 + kk * 32 + hi * 8]);
#pragma unroll
    for (int ni = 0; ni < 4; ni++)
#pragma unroll
      for (int kk = 0; kk < 2; kk++)
        bfr[ni][kk] = *(const short8*)(&Bs[(wc * 64 + ni * 16 + lo) * 64 + kk * 32 + hi * 8]);
    __builtin_amdgcn_s_setprio(1);
#pragma unroll
    for (int mi = 0; mi < 4; mi++)
#pragma unroll
      for (int ni = 0; ni < 4; ni++) {
        acc[mi][ni] = __builtin_amdgcn_mfma_f32_16x16x32_bf16(af[mi][0], bfr[ni][0], acc[mi][ni], 0, 0, 0);
        acc[mi][ni] = __builtin_amdgcn_mfma_f32_16x16x32_bf16(af[mi][1], bfr[ni][1], acc[mi][ni], 0, 0, 0);
      }
    __builtin_amdgcn_s_setprio(0);
    __syncthreads();
  }

#pragma unroll
  for (int mi = 0; mi < 4; mi++)
#pragma unroll
    for (int ni = 0; ni < 4; ni++)
#pragma unroll
      for (int r = 0; r < 4; r++) {
        int row = m0 + wr * 64 + mi * 16 + hi * 4 + r;
        int col = n0 + wc * 64 + ni * 16 + lo;
        if (MODE == 0) {
          ((float*)Out)[(size_t)row * N + col] = acc[mi][ni][r];
        } else {
          int b = row >> 11, s = row & (SEQ - 1);
          int h = col >> 6, d = col & 63;
          ((u16*)Out)[((size_t)(b * OH + h) * SEQ + s) * 64 + d] = f2b(acc[mi][ni][r]);
        }
      }
}

template<int MODE, int OH>
__global__ __launch_bounds__(256) void gemm_bt(const u16* __restrict__ A, const u16* __restrict__ W,
                                               void* __restrict__ Out, int M, int N, int K) {
  __shared__ __attribute__((aligned(16))) u16 As[128 * 64];
  __shared__ __attribute__((aligned(16))) u16 Bs[128 * 64];
  gemm_body<MODE, OH>(As, Bs, A, W, Out, M, N, K, blockIdx.x, blockIdx.y);
}

// K-proj and V-proj in one launch (blockIdx.z selects)
__global__ __launch_bounds__(256) void gemm_kv(const u16* __restrict__ A0, const u16* __restrict__ W0,
                                               u16* __restrict__ O0, const u16* __restrict__ A1,
                                               const u16* __restrict__ W1, u16* __restrict__ O1) {
  __shared__ __attribute__((aligned(16))) u16 As[128 * 64];
  __shared__ __attribute__((aligned(16))) u16 Bs[128 * 64];
  if (blockIdx.z == 0)
    gemm_body<1, NKVH>(As, Bs, A0, W0, O0, MTOK, 256, DM, blockIdx.x, blockIdx.y);
  else
    gemm_body<1, NKVH>(As, Bs, A1, W1, O1, MTOK, 256, DM, blockIdx.x, blockIdx.y);
}

// ---------------- fused RoPE (Q scaled, K) + V transpose, one launch ----------------
__global__ __launch_bounds__(256) void rope_tr(u16* __restrict__ Qb, u16* __restrict__ Kb,
                                               const float* __restrict__ cosb,
                                               const float* __restrict__ sinb,
                                               const u16* __restrict__ Vp, u16* __restrict__ Vt) {
  __shared__ __attribute__((aligned(16))) u16 T[64][68];
  int bid = blockIdx.x;
  if (bid < 2560) {
    // ---- RoPE on Q (2048 blocks) then K (512 blocks) ----
    u16* buf; float scale;
    if (bid < 2048) { buf = Qb; scale = 0.18033688f; }  // (1/8)*log2(e) folded into Q
    else { buf = Kb; scale = 1.0f; bid -= 2048; }
    int idx = bid * 256 + threadIdx.x;
    int d0 = (idx & 7) * 8;
    int s = (idx >> 3) & (SEQ - 1);
    u16* p = buf + (size_t)(idx >> 3) * 64 + d0;
    uint4 raw = *(const uint4*)p;
    u32 rw[4] = {raw.x, raw.y, raw.z, raw.w};
    float4 cv = *(const float4*)(cosb + s * 32 + (d0 >> 1));
    float4 sv = *(const float4*)(sinb + s * 32 + (d0 >> 1));
    float ca[4] = {cv.x, cv.y, cv.z, cv.w};
    float sa[4] = {sv.x, sv.y, sv.z, sv.w};
    u32 out[4];
#pragma unroll
    for (int t = 0; t < 4; t++) {
      float xr = b2f((u16)(rw[t] & 0xffff));
      float xi = b2f((u16)(rw[t] >> 16));
      float orr = (xr * ca[t] - xi * sa[t]) * scale;
      float oii = (xr * sa[t] + xi * ca[t]) * scale;
      out[t] = (u32)f2b(orr) | ((u32)f2b(oii) << 16);
    }
    uint4 ov; ov.x = out[0]; ov.y = out[1]; ov.z = out[2]; ov.w = out[3];
    *(uint4*)p = ov;
  } else {
    // ---- V transpose: (b,kh,s,d) -> (b,kh,d,s)  (256 blocks) ----
    bid -= 2560;
    int bkh = bid >> 5;
    int st = bid & 31;
    int t = threadIdx.x;
#pragma unroll
    for (int g = 0; g < 2; ++g) {
      int lin = g * 2048 + t * 8;
      int sr = lin >> 6;
      int dc = lin & 63;
      uint4 v = *(const uint4*)(Vp + ((size_t)bkh * SEQ + st * 64 + sr) * 64 + dc);
      u32 vv[4] = {v.x, v.y, v.z, v.w};
#pragma unroll
      for (int jj = 0; jj < 4; jj++) {
        T[dc + 2 * jj][sr] = (u16)(vv[jj] & 0xffff);
        T[dc + 2 * jj + 1][sr] = (u16)(vv[jj] >> 16);
      }
    }
    __syncthreads();
#pragma unroll
    for (int g = 0; g < 2; ++g) {
      int lin = g * 2048 + t * 8;
      int dr = lin >> 6;
      int sc2 = lin & 63;
      u32 ov[4];
#pragma unroll
      for (int jj = 0; jj < 4; jj++)
        ov[jj] = (u32)T[dr][sc2 + 2 * jj] | ((u32)T[dr][sc2 + 2 * jj + 1] << 16);
      uint4 q4; q4.x = ov[0]; q4.y = ov[1]; q4.z = ov[2]; q4.w = ov[3];
      *(uint4*)(Vt + ((size_t)bkh * 64 + dr) * SEQ + st * 64 + sc2) = q4;
    }
  }
}

// ---------------- Flash attention: swapped QK^T, P in registers, paired tiles ----------------
// Block owns q-tiles (p, 31-p): identical work for every block (33 units of
// 16-row x 64-kv), shared K/V fragments between the two tiles.
__device__ __forceinline__ void softmax_pv(f32x4 (&sc)[4], float& m, float& lsp, f32x4 (&o)[4],
                                           const short8* vb0, const short8* vb1, int hi) {
  float lm = sc[0][0];
#pragma unroll
  for (int f = 0; f < 4; f++)
#pragma unroll
    for (int r = 0; r < 4; r++) lm = fmaxf(lm, sc[f][r]);
  if (__any(lm - m > 8.f)) {
    float mx = fmaxf(m, lm);
    mx = fmaxf(mx, __shfl_xor(mx, 16, 64));
    mx = fmaxf(mx, __shfl_xor(mx, 32, 64));
    float corr = exp2f(m - mx);
    m = mx;
    lsp *= corr;
    float corrq[4];
#pragma unroll
    for (int r = 0; r < 4; r++) corrq[r] = __shfl(corr, hi * 4 + r, 64);
#pragma unroll
    for (int nf = 0; nf < 4; nf++)
#pragma unroll
      for (int r = 0; r < 4; r++) o[nf][r] *= corrq[r];
  }
  float pv2[4][4];
#pragma unroll
  for (int f = 0; f < 4; f++)
#pragma unroll
    for (int r = 0; r < 4; r++) {
      pv2[f][r] = exp2f(sc[f][r] - m);
      lsp += pv2[f][r];
    }
  union { u32 u[4]; short8 s8; } pa0, pa1;
#pragma unroll
  for (int t = 0; t < 4; t++) {
    int fsel = t >> 1, r0 = 2 * (t & 1);
    pa0.u[t] = cvtpk(pv2[fsel][r0], pv2[fsel][r0 + 1]);
    pa1.u[t] = cvtpk(pv2[2 + fsel][r0], pv2[2 + fsel][r0 + 1]);
  }
  __builtin_amdgcn_s_setprio(1);
#pragma unroll
  for (int nf = 0; nf < 4; nf++) {
    o[nf] = __builtin_amdgcn_mfma_f32_16x16x32_bf16(pa0.s8, vb0[nf], o[nf], 0, 0, 0);
    o[nf] = __builtin_amdgcn_mfma_f32_16x16x32_bf16(pa1.s8, vb1[nf], o[nf], 0, 0, 0);
  }
  __builtin_amdgcn_s_setprio(0);
}

__global__ __launch_bounds__(256, 2) void attn_kernel(const u16* __restrict__ Q, const u16* __restrict__ Kb,
                                                      const u16* __restrict__ Vt, u16* __restrict__ AO) {
  __shared__ __attribute__((aligned(16))) u16 Ks[2][4096];  // [kv 64][d 64] swizzled
  __shared__ __attribute__((aligned(16))) u16 Vs[2][4096];  // [d 64][kv 64] swizzled
  const int tid = threadIdx.x;
  const int w = tid >> 6, lane = tid & 63;
  const int lo = lane & 15, hi = lane >> 4;
  const int bh = blockIdx.x;
  const int b = bh >> 4, h = bh & 15, kh = h >> 2;
  const int p = blockIdx.y;           // pair index 0..15
  const int tA = p, tB = 31 - p;      // short tile, long tile
  const int q0A = tA * 64 + w * 16;
  const int q0B = tB * 64 + w * 16;
  const u16* Qp = Q + (size_t)bh * SEQ * 64;
  const u16* Kp = Kb + (size_t)(b * NKVH + kh) * SEQ * 64;
  const u16* Vp = Vt + (size_t)(b * NKVH + kh) * 64 * SEQ;

  short8 qfA[2], qfB[2];
#pragma unroll
  for (int kk = 0; kk < 2; kk++) {
    qfA[kk] = *(const short8*)(Qp + (size_t)(q0A + lo) * 64 + kk * 32 + hi * 8);
    qfB[kk] = *(const short8*)(Qp + (size_t)(q0B + lo) * 64 + kk * 32 + hi * 8);
  }

  f32x4 oA[4], oB[4];
#pragma unroll
  for (int nf = 0; nf < 4; nf++) { oA[nf] = (f32x4){0.f,0.f,0.f,0.f}; oB[nf] = (f32x4){0.f,0.f,0.f,0.f}; }
  float mA = -__builtin_inff(), lspA = 0.f;
  float mB = -__builtin_inff(), lspB = 0.f;

  auto key = [](int row) { return (row & 3) | (((row >> 3) & 1) << 2); };
  auto stage = [&](int kv0, int bufi) {
#pragma unroll
    for (int s = 0; s < 2; s++) {
      int base = s * 4096 + w * 1024;
      int o2 = base + (lane << 4);
      int row = o2 >> 7;
      int gg = ((o2 >> 4) & 7) ^ key(row);
      gload16(Kp + (size_t)(kv0 + row) * 64 + gg * 8, (char*)&Ks[bufi][0] + base);
      gload16(Vp + (size_t)row * SEQ + kv0 + gg * 8, (char*)&Vs[bufi][0] + base);
    }
  };
  auto lds8 = [&](const u16* S, int row, int col8) {
    return *(const short8*)(S + row * 64 + (col8 ^ (key(row) << 3)));
  };

  int krow[4];
#pragma unroll
  for (int f = 0; f < 4; f++)
    krow[f] = 32 * (f >> 1) + 8 * (lo >> 2) + 4 * (f & 1) + (lo & 3);

  const int nt = tB + 1;
  stage(0, 0);
  __syncthreads();

  for (int c = 0; c < nt; ++c) {
    const int cur = c & 1;
    const int kv0 = c * 64;
    if (c + 1 < nt) stage(kv0 + 64, cur ^ 1);

    // K fragments (shared by both tiles)
    short8 kf0[4], kf1[4];
#pragma unroll
    for (int f = 0; f < 4; f++) {
      kf0[f] = lds8(&Ks[cur][0], krow[f], hi * 8);
      kf1[f] = lds8(&Ks[cur][0], krow[f], 32 + hi * 8);
    }
    const bool actA = (c <= tA);

    // QK^T for tile B (always) and tile A (while active)
    f32x4 scB[4], scA[4];
#pragma unroll
    for (int f = 0; f < 4; f++) scB[f] = (f32x4){0.f,0.f,0.f,0.f};
    __builtin_amdgcn_s_setprio(1);
#pragma unroll
    for (int f = 0; f < 4; f++) {
      scB[f] = __builtin_amdgcn_mfma_f32_16x16x32_bf16(kf0[f], qfB[0], scB[f], 0, 0, 0);
      scB[f] = __builtin_amdgcn_mfma_f32_16x16x32_bf16(kf1[f], qfB[1], scB[f], 0, 0, 0);
    }
    __builtin_amdgcn_s_setprio(0);
    if (actA) {
#pragma unroll
      for (int f = 0; f < 4; f++) scA[f] = (f32x4){0.f,0.f,0.f,0.f};
      __builtin_amdgcn_s_setprio(1);
#pragma unroll
      for (int f = 0; f < 4; f++) {
        scA[f] = __builtin_amdgcn_mfma_f32_16x16x32_bf16(kf0[f], qfA[0], scA[f], 0, 0, 0);
        scA[f] = __builtin_amdgcn_mfma_f32_16x16x32_bf16(kf1[f], qfA[1], scA[f], 0, 0, 0);
      }
      __builtin_amdgcn_s_setprio(0);
    }

    // V fragments (shared by both tiles)
    short8 vb0[4], vb1[4];
#pragma unroll
    for (int nf = 0; nf < 4; nf++) {
      vb0[nf] = lds8(&Vs[cur][0], nf * 16 + lo, hi * 8);
      vb1[nf] = lds8(&Vs[cur][0], nf * 16 + lo, 32 + hi * 8);
    }

    // causal masks on straddling chunks (c == tile index)
    if (c == tB) {
#pragma unroll
      for (int f = 0; f < 4; f++) {
        int kvb = kv0 + 32 * (f >> 1) + 8 * hi + 4 * (f & 1);
#pragma unroll
        for (int r = 0; r < 4; r++)
          if (kvb + r > q0B + lo) scB[f][r] = -__builtin_inff();
      }
    }
    softmax_pv(scB, mB, lspB, oB, vb0, vb1, hi);

    if (actA) {
      if (c == tA) {
#pragma unroll
        for (int f = 0; f < 4; f++) {
          int kvb = kv0 + 32 * (f >> 1) + 8 * hi + 4 * (f & 1);
#pragma unroll
          for (int r = 0; r < 4; r++)
            if (kvb + r > q0A + lo) scA[f][r] = -__builtin_inff();
        }
      }
      softmax_pv(scA, mA, lspA, oA, vb0, vb1, hi);
    }
    __syncthreads();
  }

  // finalize both tiles
#pragma unroll
  for (int t2 = 0; t2 < 2; t2++) {
    float lsp = t2 ? lspB : lspA;
    const int q0 = t2 ? q0B : q0A;
    f32x4* o = t2 ? oB : oA;
    lsp += __shfl_xor(lsp, 16, 64);
    lsp += __shfl_xor(lsp, 32, 64);
    float inv = 1.0f / lsp;
    float invq[4];
#pragma unroll
    for (int r = 0; r < 4; r++) invq[r] = __shfl(inv, hi * 4 + r, 64);
#pragma unroll
    for (int nf = 0; nf < 4; nf++)
#pragma unroll
      for (int r = 0; r < 4; r++) {
        int q = q0 + hi * 4 + r;
        int d = nf * 16 + lo;
        AO[((size_t)(b * SEQ + q) * NHEADS + h) * 64 + d] = f2b(o[nf][r] * invq[r]);
      }
  }
}

extern "C" void kernel_launch(void* const* d_in, const int* in_sizes, int n_in,
                              void* d_out, int out_size, void* d_ws, size_t ws_size,
                              hipStream_t stream) {
  const float* query = (const float*)d_in[0];
  const float* key_ = (const float*)d_in[1];
  const float* value = (const float*)d_in[2];
  const float* fcos = (const float*)d_in[3];
  const float* fsin = (const float*)d_in[4];
  const float* wq = (const float*)d_in[5];
  const float* wk = (const float*)d_in[6];
  const float* wv = (const float*)d_in[7];
  const float* wo = (const float*)d_in[8];

  char* ws = (char*)d_ws;
  size_t off = 0;
  auto alloc = [&](size_t elems) {
    u16* p = (u16*)(ws + off);
    off = (off + elems * 2 + 255) & ~(size_t)255;
    return p;
  };
  u16* qf = alloc((size_t)MTOK * DM);
  u16* kf = alloc((size_t)MTOK * DM);
  u16* vf = alloc((size_t)MTOK * DM);
  u16* wqf = alloc((size_t)DM * DM);
  u16* wkf = alloc((size_t)256 * DM);
  u16* wvf = alloc((size_t)256 * DM);
  u16* wof = alloc((size_t)DM * DM);
  u16* Qr = alloc((size_t)MTOK * DM);            // (b,h,s,d)
  u16* Kr = alloc((size_t)NB * NKVH * SEQ * 64); // (b,kh,s,d)
  u16* Vp = alloc((size_t)NB * NKVH * SEQ * 64); // (b,kh,s,d)
  u16* Vt = alloc((size_t)NB * NKVH * 64 * SEQ); // (b,kh,d,s)
  u16* AO = alloc((size_t)MTOK * DM);            // (b,s,h,d)

  cvt_all<<<3 * 2048 + 1280, 256, 0, stream>>>(query, key_, value, wq, wk, wv, wo,
                                               qf, kf, vf, wqf, wkf, wvf, wof);

  gemm_bt<1, NHEADS><<<dim3(DM / 128, MTOK / 128), 256, 0, stream>>>(qf, wqf, Qr, MTOK, DM, DM);
  gemm_kv<<<dim3(2, MTOK / 128, 2), 256, 0, stream>>>(kf, wkf, Kr, vf, wvf, Vp);

  rope_tr<<<2560 + 256, 256, 0, stream>>>(Qr, Kr, fcos, fsin, Vp, Vt);

  attn_kernel<<<dim3(NB * NHEADS, 16), 256, 0, stream>>>(Qr, Kr, Vt, AO);

  gemm_bt<0, 0><<<dim3(DM / 128, MTOK / 128), 256, 0, stream>>>(AO, wof, d_out, MTOK, DM, DM);
}

// Round 6
// 116.511 us; speedup vs baseline: 3.0446x; 1.1680x over previous
//
#include <hip/hip_runtime.h>

#define DM 1024
#define NHEADS 16
#define NKVH 4
#define HDIM 64
#define NB 2
#define SEQ 2048
#define MTOK (NB*SEQ)

typedef __attribute__((ext_vector_type(4))) float f32x4;
typedef __attribute__((ext_vector_type(8))) short short8;
typedef unsigned short u16;
typedef unsigned int u32;

__device__ __forceinline__ float b2f(u16 u) {
  u32 i = ((u32)u) << 16; float f; __builtin_memcpy(&f, &i, 4); return f;
}
__device__ __forceinline__ u16 f2b(float f) {
  u32 i; __builtin_memcpy(&i, &f, 4);
  u32 r = i + 0x7fffu + ((i >> 16) & 1u);
  return (u16)(r >> 16);
}
__device__ __forceinline__ u32 cvtpk(float a, float b) {  // low16=bf16(a), high16=bf16(b)
  u32 r; asm("v_cvt_pk_bf16_f32 %0, %1, %2" : "=v"(r) : "v"(a), "v"(b)); return r;
}
__device__ __forceinline__ void gload16(const void* g, void* l) {
  __builtin_amdgcn_global_load_lds((const __attribute__((address_space(1))) u32*)g,
                                   (__attribute__((address_space(3))) u32*)l, 16, 0, 0);
}

// ---- fp32 tile staging: 128 rows x 64 cols, K(ld)=1024, via regs + cvt_pk ----
__device__ __forceinline__ void stage_regs_f32(const float* __restrict__ base, int k0, int t, float4* r) {
  const int row = t >> 3;
  const int c0 = (t & 7) * 4;
#pragma unroll
  for (int s = 0; s < 4; s++) {
    const float* p = base + (size_t)(s * 32 + row) * DM + k0 + c0;
    r[2 * s] = *(const float4*)p;
    r[2 * s + 1] = *(const float4*)(p + 32);
  }
}
__device__ __forceinline__ void stage_lds_f32(u16* Ls, int t, const float4* r) {
  const int row = t >> 3;
  const int c0 = (t & 7) * 4;
#pragma unroll
  for (int s = 0; s < 4; s++) {
    u32 w0[2] = {cvtpk(r[2 * s].x, r[2 * s].y), cvtpk(r[2 * s].z, r[2 * s].w)};
    u32 w1[2] = {cvtpk(r[2 * s + 1].x, r[2 * s + 1].y), cvtpk(r[2 * s + 1].z, r[2 * s + 1].w)};
    *(uint2*)&Ls[(s * 32 + row) * 64 + c0] = *(uint2*)w0;
    *(uint2*)&Ls[(s * 32 + row) * 64 + 32 + c0] = *(uint2*)w1;
  }
}

// ---------------- fused QKV projection GEMM + RoPE + V-transpose ----------------
// grid (12, 32): bx 0..7 -> Q (+rope, scaled), 8..9 -> K (+rope), 10..11 -> V (transposed store)
__global__ __launch_bounds__(256) void gemm_qkv(const float* __restrict__ Aq, const float* __restrict__ Ak,
                                                const float* __restrict__ Av, const float* __restrict__ wq,
                                                const float* __restrict__ wk, const float* __restrict__ wv,
                                                const float* __restrict__ cosb, const float* __restrict__ sinb,
                                                u16* __restrict__ Qr, u16* __restrict__ Kr,
                                                u16* __restrict__ Vt) {
  __shared__ __attribute__((aligned(16))) u16 SH[16384];
  u16* As = SH;
  u16* Bs = SH + 8192;
  const int bx = blockIdx.x, by = blockIdx.y, tid = threadIdx.x;
  const int lane = tid & 63, w = tid >> 6;
  const int wr = w >> 1, wc = w & 1;
  const int lo = lane & 15, hi = lane >> 4;
  const int m0 = by * 128;

  const float* Ap;
  const float* Wp;
  int n0, mode;
  if (bx < 8) { Ap = Aq; Wp = wq; n0 = bx * 128; mode = 0; }
  else if (bx < 10) { Ap = Ak; Wp = wk; n0 = (bx - 8) * 128; mode = 1; }
  else { Ap = Av; Wp = wv; n0 = (bx - 10) * 128; mode = 2; }

  f32x4 acc[4][4];
#pragma unroll
  for (int i = 0; i < 4; i++)
#pragma unroll
    for (int j = 0; j < 4; j++) acc[i][j] = (f32x4){0.f, 0.f, 0.f, 0.f};

  const float* Abase = Ap + (size_t)m0 * DM;
  const float* Wbase = Wp + (size_t)n0 * DM;

  float4 ra[8], rb[8];
  stage_regs_f32(Abase, 0, tid, ra);
  stage_regs_f32(Wbase, 0, tid, rb);

  for (int ks = 0; ks < 16; ks++) {
    stage_lds_f32(As, tid, ra);
    stage_lds_f32(Bs, tid, rb);
    __syncthreads();
    if (ks < 15) {
      stage_regs_f32(Abase, (ks + 1) * 64, tid, ra);
      stage_regs_f32(Wbase, (ks + 1) * 64, tid, rb);
    }
    short8 af[4][2], bfr[4][2];
#pragma unroll
    for (int mi = 0; mi < 4; mi++)
#pragma unroll
      for (int kk = 0; kk < 2; kk++)
        af[mi][kk] = *(const short8*)(&As[(wr * 64 + mi * 16 + lo) * 64 + kk * 32 + hi * 8]);
#pragma unroll
    for (int ni = 0; ni < 4; ni++)
#pragma unroll
      for (int kk = 0; kk < 2; kk++)
        bfr[ni][kk] = *(const short8*)(&Bs[(wc * 64 + ni * 16 + lo) * 64 + kk * 32 + hi * 8]);
    __builtin_amdgcn_s_setprio(1);
#pragma unroll
    for (int mi = 0; mi < 4; mi++)
#pragma unroll
      for (int ni = 0; ni < 4; ni++) {
        acc[mi][ni] = __builtin_amdgcn_mfma_f32_16x16x32_bf16(af[mi][0], bfr[ni][0], acc[mi][ni], 0, 0, 0);
        acc[mi][ni] = __builtin_amdgcn_mfma_f32_16x16x32_bf16(af[mi][1], bfr[ni][1], acc[mi][ni], 0, 0, 0);
      }
    __builtin_amdgcn_s_setprio(0);
    __syncthreads();
  }

  if (mode < 2) {
    // ---- RoPE epilogue -> Qr (b,h,s,d) or Kr (b,kh,s,d) ----
    const float scale = (mode == 0) ? 0.18033688f : 1.0f;  // Q: (1/8)*log2(e)
    u16* outp = (mode == 0) ? Qr : Kr;
    const int OH = (mode == 0) ? NHEADS : NKVH;
    const int h = (n0 >> 6) + wc;
    const float sgn = (lo & 1) ? 1.0f : -1.0f;
#pragma unroll
    for (int ni = 0; ni < 4; ni++) {
      const int d = ni * 16 + lo;
      const int j = d >> 1;
#pragma unroll
      for (int mi = 0; mi < 4; mi++)
#pragma unroll
        for (int r = 0; r < 4; r++) {
          int row = m0 + wr * 64 + mi * 16 + hi * 4 + r;
          int srow = row & (SEQ - 1), bb = row >> 11;
          float v = acc[mi][ni][r];
          float pv = __shfl_xor(v, 1, 64);
          float c = cosb[srow * 32 + j];
          float s = sinb[srow * 32 + j];
          float ov = (v * c + pv * s * sgn) * scale;
          outp[((size_t)(bb * OH + h) * SEQ + srow) * 64 + d] = f2b(ov);
        }
    }
  } else {
    // ---- V epilogue: transpose via LDS -> Vt (b,kh,d,s) ----
    u16* Tt = SH;  // 128x128 u16 = 32 KB
#pragma unroll
    for (int mi = 0; mi < 4; mi++)
#pragma unroll
      for (int ni = 0; ni < 4; ni++) {
        const int cl = wc * 64 + ni * 16 + lo;
        const int kx = (cl & 15) << 2;
#pragma unroll
        for (int r = 0; r < 4; r++) {
          int rl = wr * 64 + mi * 16 + hi * 4 + r;
          Tt[cl * 128 + (rl ^ kx)] = f2b(acc[mi][ni][r]);
        }
      }
    __syncthreads();
    const int dl = tid >> 1;            // feature row 0..127
    const int sh = (tid & 1) * 64;      // s-half
    const int bb = m0 >> 11, sbase = m0 & (SEQ - 1);
    const int vrow = (bb * NKVH + (n0 >> 6) + (dl >> 6)) * 64 + (dl & 63);
    u16* dst = Vt + (size_t)vrow * SEQ + sbase + sh;
    const int K4 = (dl & 15) << 2;
#pragma unroll
    for (int i = 0; i < 8; i++) {
      uint2 a4 = *(const uint2*)&Tt[dl * 128 + ((sh + i * 8) ^ K4)];
      uint2 b4 = *(const uint2*)&Tt[dl * 128 + ((sh + i * 8 + 4) ^ K4)];
      uint4 o4; o4.x = a4.x; o4.y = a4.y; o4.z = b4.x; o4.w = b4.y;
      *(uint4*)(dst + i * 8) = o4;
    }
  }
}

// ---------------- Flash attention (unchanged from R5) ----------------
__device__ __forceinline__ void softmax_pv(f32x4 (&sc)[4], float& m, float& lsp, f32x4 (&o)[4],
                                           const short8* vb0, const short8* vb1, int hi) {
  float lm = sc[0][0];
#pragma unroll
  for (int f = 0; f < 4; f++)
#pragma unroll
    for (int r = 0; r < 4; r++) lm = fmaxf(lm, sc[f][r]);
  if (__any(lm - m > 8.f)) {
    float mx = fmaxf(m, lm);
    mx = fmaxf(mx, __shfl_xor(mx, 16, 64));
    mx = fmaxf(mx, __shfl_xor(mx, 32, 64));
    float corr = exp2f(m - mx);
    m = mx;
    lsp *= corr;
    float corrq[4];
#pragma unroll
    for (int r = 0; r < 4; r++) corrq[r] = __shfl(corr, hi * 4 + r, 64);
#pragma unroll
    for (int nf = 0; nf < 4; nf++)
#pragma unroll
      for (int r = 0; r < 4; r++) o[nf][r] *= corrq[r];
  }
  float pv2[4][4];
#pragma unroll
  for (int f = 0; f < 4; f++)
#pragma unroll
    for (int r = 0; r < 4; r++) {
      pv2[f][r] = exp2f(sc[f][r] - m);
      lsp += pv2[f][r];
    }
  union { u32 u[4]; short8 s8; } pa0, pa1;
#pragma unroll
  for (int t = 0; t < 4; t++) {
    int fsel = t >> 1, r0 = 2 * (t & 1);
    pa0.u[t] = cvtpk(pv2[fsel][r0], pv2[fsel][r0 + 1]);
    pa1.u[t] = cvtpk(pv2[2 + fsel][r0], pv2[2 + fsel][r0 + 1]);
  }
  __builtin_amdgcn_s_setprio(1);
#pragma unroll
  for (int nf = 0; nf < 4; nf++) {
    o[nf] = __builtin_amdgcn_mfma_f32_16x16x32_bf16(pa0.s8, vb0[nf], o[nf], 0, 0, 0);
    o[nf] = __builtin_amdgcn_mfma_f32_16x16x32_bf16(pa1.s8, vb1[nf], o[nf], 0, 0, 0);
  }
  __builtin_amdgcn_s_setprio(0);
}

__global__ __launch_bounds__(256, 2) void attn_kernel(const u16* __restrict__ Q, const u16* __restrict__ Kb,
                                                      const u16* __restrict__ Vt, u16* __restrict__ AO) {
  __shared__ __attribute__((aligned(16))) u16 Ks[2][4096];
  __shared__ __attribute__((aligned(16))) u16 Vs[2][4096];
  const int tid = threadIdx.x;
  const int w = tid >> 6, lane = tid & 63;
  const int lo = lane & 15, hi = lane >> 4;
  const int bh = blockIdx.x;
  const int b = bh >> 4, h = bh & 15, kh = h >> 2;
  const int p = blockIdx.y;
  const int tA = p, tB = 31 - p;
  const int q0A = tA * 64 + w * 16;
  const int q0B = tB * 64 + w * 16;
  const u16* Qp = Q + (size_t)bh * SEQ * 64;
  const u16* Kp = Kb + (size_t)(b * NKVH + kh) * SEQ * 64;
  const u16* Vp = Vt + (size_t)(b * NKVH + kh) * 64 * SEQ;

  short8 qfA[2], qfB[2];
#pragma unroll
  for (int kk = 0; kk < 2; kk++) {
    qfA[kk] = *(const short8*)(Qp + (size_t)(q0A + lo) * 64 + kk * 32 + hi * 8);
    qfB[kk] = *(const short8*)(Qp + (size_t)(q0B + lo) * 64 + kk * 32 + hi * 8);
  }

  f32x4 oA[4], oB[4];
#pragma unroll
  for (int nf = 0; nf < 4; nf++) { oA[nf] = (f32x4){0.f,0.f,0.f,0.f}; oB[nf] = (f32x4){0.f,0.f,0.f,0.f}; }
  float mA = -__builtin_inff(), lspA = 0.f;
  float mB = -__builtin_inff(), lspB = 0.f;

  auto key = [](int row) { return (row & 3) | (((row >> 3) & 1) << 2); };
  auto stage = [&](int kv0, int bufi) {
#pragma unroll
    for (int s = 0; s < 2; s++) {
      int base = s * 4096 + w * 1024;
      int o2 = base + (lane << 4);
      int row = o2 >> 7;
      int gg = ((o2 >> 4) & 7) ^ key(row);
      gload16(Kp + (size_t)(kv0 + row) * 64 + gg * 8, (char*)&Ks[bufi][0] + base);
      gload16(Vp + (size_t)row * SEQ + kv0 + gg * 8, (char*)&Vs[bufi][0] + base);
    }
  };
  auto lds8 = [&](const u16* S, int row, int col8) {
    return *(const short8*)(S + row * 64 + (col8 ^ (key(row) << 3)));
  };

  int krow[4];
#pragma unroll
  for (int f = 0; f < 4; f++)
    krow[f] = 32 * (f >> 1) + 8 * (lo >> 2) + 4 * (f & 1) + (lo & 3);

  const int nt = tB + 1;
  stage(0, 0);
  __syncthreads();

  for (int c = 0; c < nt; ++c) {
    const int cur = c & 1;
    const int kv0 = c * 64;
    if (c + 1 < nt) stage(kv0 + 64, cur ^ 1);

    short8 kf0[4], kf1[4];
#pragma unroll
    for (int f = 0; f < 4; f++) {
      kf0[f] = lds8(&Ks[cur][0], krow[f], hi * 8);
      kf1[f] = lds8(&Ks[cur][0], krow[f], 32 + hi * 8);
    }
    const bool actA = (c <= tA);

    f32x4 scB[4], scA[4];
#pragma unroll
    for (int f = 0; f < 4; f++) scB[f] = (f32x4){0.f,0.f,0.f,0.f};
    __builtin_amdgcn_s_setprio(1);
#pragma unroll
    for (int f = 0; f < 4; f++) {
      scB[f] = __builtin_amdgcn_mfma_f32_16x16x32_bf16(kf0[f], qfB[0], scB[f], 0, 0, 0);
      scB[f] = __builtin_amdgcn_mfma_f32_16x16x32_bf16(kf1[f], qfB[1], scB[f], 0, 0, 0);
    }
    __builtin_amdgcn_s_setprio(0);
    if (actA) {
#pragma unroll
      for (int f = 0; f < 4; f++) scA[f] = (f32x4){0.f,0.f,0.f,0.f};
      __builtin_amdgcn_s_setprio(1);
#pragma unroll
      for (int f = 0; f < 4; f++) {
        scA[f] = __builtin_amdgcn_mfma_f32_16x16x32_bf16(kf0[f], qfA[0], scA[f], 0, 0, 0);
        scA[f] = __builtin_amdgcn_mfma_f32_16x16x32_bf16(kf1[f], qfA[1], scA[f], 0, 0, 0);
      }
      __builtin_amdgcn_s_setprio(0);
    }

    short8 vb0[4], vb1[4];
#pragma unroll
    for (int nf = 0; nf < 4; nf++) {
      vb0[nf] = lds8(&Vs[cur][0], nf * 16 + lo, hi * 8);
      vb1[nf] = lds8(&Vs[cur][0], nf * 16 + lo, 32 + hi * 8);
    }

    if (c == tB) {
#pragma unroll
      for (int f = 0; f < 4; f++) {
        int kvb = kv0 + 32 * (f >> 1) + 8 * hi + 4 * (f & 1);
#pragma unroll
        for (int r = 0; r < 4; r++)
          if (kvb + r > q0B + lo) scB[f][r] = -__builtin_inff();
      }
    }
    softmax_pv(scB, mB, lspB, oB, vb0, vb1, hi);

    if (actA) {
      if (c == tA) {
#pragma unroll
        for (int f = 0; f < 4; f++) {
          int kvb = kv0 + 32 * (f >> 1) + 8 * hi + 4 * (f & 1);
#pragma unroll
          for (int r = 0; r < 4; r++)
            if (kvb + r > q0A + lo) scA[f][r] = -__builtin_inff();
        }
      }
      softmax_pv(scA, mA, lspA, oA, vb0, vb1, hi);
    }
    __syncthreads();
  }

#pragma unroll
  for (int t2 = 0; t2 < 2; t2++) {
    float lsp = t2 ? lspB : lspA;
    const int q0 = t2 ? q0B : q0A;
    f32x4* o = t2 ? oB : oA;
    lsp += __shfl_xor(lsp, 16, 64);
    lsp += __shfl_xor(lsp, 32, 64);
    float inv = 1.0f / lsp;
    float invq[4];
#pragma unroll
    for (int r = 0; r < 4; r++) invq[r] = __shfl(inv, hi * 4 + r, 64);
#pragma unroll
    for (int nf = 0; nf < 4; nf++)
#pragma unroll
      for (int r = 0; r < 4; r++) {
        int q = q0 + hi * 4 + r;
        int d = nf * 16 + lo;
        AO[((size_t)(b * SEQ + q) * NHEADS + h) * 64 + d] = f2b(o[nf][r] * invq[r]);
      }
  }
}

// ---------------- output projection: d_out[M,1024] = AO[M,1024](bf16) @ wo^T(fp32) ----------------
__global__ __launch_bounds__(256) void gemm_out(const u16* __restrict__ A, const float* __restrict__ W,
                                                float* __restrict__ Out) {
  __shared__ __attribute__((aligned(16))) u16 As[8192];
  __shared__ __attribute__((aligned(16))) u16 Bs[8192];
  const int tid = threadIdx.x;
  const int lane = tid & 63, w = tid >> 6;
  const int wr = w >> 1, wc = w & 1;
  const int lo = lane & 15, hi = lane >> 4;
  const int m0 = blockIdx.y * 128, n0 = blockIdx.x * 128;
  const int crow = lane >> 3;
  const int ccol = (lane & 7) * 8;

  f32x4 acc[4][4];
#pragma unroll
  for (int i = 0; i < 4; i++)
#pragma unroll
    for (int j = 0; j < 4; j++) acc[i][j] = (f32x4){0.f, 0.f, 0.f, 0.f};

  const float* Wbase = W + (size_t)n0 * DM;
  float4 rb[8];
  stage_regs_f32(Wbase, 0, tid, rb);

  for (int ks = 0; ks < 16; ks++) {
    const int k0 = ks * 64;
#pragma unroll
    for (int cc = 0; cc < 4; ++cc) {
      int c = w * 4 + cc;
      gload16(A + (size_t)(m0 + c * 8 + crow) * DM + k0 + ccol, &As[c * 512]);
    }
    stage_lds_f32(Bs, tid, rb);
    __syncthreads();
    if (ks < 15) stage_regs_f32(Wbase, k0 + 64, tid, rb);
    short8 af[4][2], bfr[4][2];
#pragma unroll
    for (int mi = 0; mi < 4; mi++)
#pragma unroll
      for (int kk = 0; kk < 2; kk++)
        af[mi][kk] = *(const short8*)(&As[(wr * 64 + mi * 16 + lo) * 64 + kk * 32 + hi * 8]);
#pragma unroll
    for (int ni = 0; ni < 4; ni++)
#pragma unroll
      for (int kk = 0; kk < 2; kk++)
        bfr[ni][kk] = *(const short8*)(&Bs[(wc * 64 + ni * 16 + lo) * 64 + kk * 32 + hi * 8]);
    __builtin_amdgcn_s_setprio(1);
#pragma unroll
    for (int mi = 0; mi < 4; mi++)
#pragma unroll
      for (int ni = 0; ni < 4; ni++) {
        acc[mi][ni] = __builtin_amdgcn_mfma_f32_16x16x32_bf16(af[mi][0], bfr[ni][0], acc[mi][ni], 0, 0, 0);
        acc[mi][ni] = __builtin_amdgcn_mfma_f32_16x16x32_bf16(af[mi][1], bfr[ni][1], acc[mi][ni], 0, 0, 0);
      }
    __builtin_amdgcn_s_setprio(0);
    __syncthreads();
  }

#pragma unroll
  for (int mi = 0; mi < 4; mi++)
#pragma unroll
    for (int ni = 0; ni < 4; ni++)
#pragma unroll
      for (int r = 0; r < 4; r++) {
        int row = m0 + wr * 64 + mi * 16 + hi * 4 + r;
        int col = n0 + wc * 64 + ni * 16 + lo;
        Out[(size_t)row * DM + col] = acc[mi][ni][r];
      }
}

extern "C" void kernel_launch(void* const* d_in, const int* in_sizes, int n_in,
                              void* d_out, int out_size, void* d_ws, size_t ws_size,
                              hipStream_t stream) {
  const float* query = (const float*)d_in[0];
  const float* key_ = (const float*)d_in[1];
  const float* value = (const float*)d_in[2];
  const float* fcos = (const float*)d_in[3];
  const float* fsin = (const float*)d_in[4];
  const float* wq = (const float*)d_in[5];
  const float* wk = (const float*)d_in[6];
  const float* wv = (const float*)d_in[7];
  const float* wo = (const float*)d_in[8];

  char* ws = (char*)d_ws;
  size_t off = 0;
  auto alloc = [&](size_t elems) {
    u16* p = (u16*)(ws + off);
    off = (off + elems * 2 + 255) & ~(size_t)255;
    return p;
  };
  u16* Qr = alloc((size_t)MTOK * DM);            // (b,h,s,d) rope'd + scaled
  u16* Kr = alloc((size_t)NB * NKVH * SEQ * 64); // (b,kh,s,d) rope'd
  u16* Vt = alloc((size_t)NB * NKVH * 64 * SEQ); // (b,kh,d,s)
  u16* AO = alloc((size_t)MTOK * DM);            // (b,s,h,d)

  gemm_qkv<<<dim3(12, MTOK / 128), 256, 0, stream>>>(query, key_, value, wq, wk, wv,
                                                     fcos, fsin, Qr, Kr, Vt);

  attn_kernel<<<dim3(NB * NHEADS, 16), 256, 0, stream>>>(Qr, Kr, Vt, AO);

  gemm_out<<<dim3(DM / 128, MTOK / 128), 256, 0, stream>>>(AO, wo, (float*)d_out);
}

// Round 7
// 98.882 us; speedup vs baseline: 3.5875x; 1.1783x over previous
//
#include <hip/hip_runtime.h>

#define DM 1024
#define NHEADS 16
#define NKVH 4
#define HDIM 64
#define NB 2
#define SEQ 2048
#define MTOK (NB*SEQ)

typedef __attribute__((ext_vector_type(4))) float f32x4;
typedef __attribute__((ext_vector_type(8))) short short8;
typedef unsigned short u16;
typedef unsigned int u32;

__device__ __forceinline__ u16 f2b(float f) {
  u32 i; __builtin_memcpy(&i, &f, 4);
  u32 r = i + 0x7fffu + ((i >> 16) & 1u);
  return (u16)(r >> 16);
}
__device__ __forceinline__ u32 cvtpk(float a, float b) {  // low16=bf16(a), high16=bf16(b)
  u32 r; asm("v_cvt_pk_bf16_f32 %0, %1, %2" : "=v"(r) : "v"(a), "v"(b)); return r;
}
__device__ __forceinline__ void gload16(const void* g, void* l) {
  __builtin_amdgcn_global_load_lds((const __attribute__((address_space(1))) u32*)g,
                                   (__attribute__((address_space(3))) u32*)l, 16, 0, 0);
}

// ---------------- fused QKV projection GEMM + RoPE + V-transpose ----------------
// grid (64, 12): bx = m-tile (64 rows); by 0..7 -> Q (+rope,scaled), 8..9 -> K (+rope),
// 10..11 -> V (transposed store). LDS rows stride 72 u16 (bank-conflict-free staging).
__global__ __launch_bounds__(256) void gemm_qkv(const float* __restrict__ Aq, const float* __restrict__ Ak,
                                                const float* __restrict__ Av, const float* __restrict__ wq,
                                                const float* __restrict__ wk, const float* __restrict__ wv,
                                                const float* __restrict__ cosb, const float* __restrict__ sinb,
                                                u16* __restrict__ Qr, u16* __restrict__ Kr,
                                                u16* __restrict__ Vt) {
  __shared__ __attribute__((aligned(16))) u16 SH[13824];  // As[64][72] + Bs[128][72]
  u16* As = SH;
  u16* Bs = SH + 4608;
  const int tid = threadIdx.x, lane = tid & 63, w = tid >> 6;
  const int wr = w >> 1, wc = w & 1, lo = lane & 15, hi = lane >> 4;
  const int bx = blockIdx.x, by = blockIdx.y;
  const int m0 = bx * 64;

  const float *Ap, *Wp;
  int n0, mode;
  if (by < 8) { Ap = Aq; Wp = wq; n0 = by * 128; mode = 0; }
  else if (by < 10) { Ap = Ak; Wp = wk; n0 = (by - 8) * 128; mode = 1; }
  else { Ap = Av; Wp = wv; n0 = (by - 10) * 128; mode = 2; }

  const int srw = tid >> 2, sc0 = (tid & 3) * 4;  // staging: row, col base (elems)
  const float* Abase = Ap + (size_t)(m0 + srw) * DM + sc0;
  const float* Wbase = Wp + (size_t)(n0 + srw) * DM + sc0;

  f32x4 acc[2][4];
#pragma unroll
  for (int i = 0; i < 2; i++)
#pragma unroll
    for (int j = 0; j < 4; j++) acc[i][j] = (f32x4){0.f, 0.f, 0.f, 0.f};

  float4 ra[4], rb[8];
#pragma unroll
  for (int j = 0; j < 4; j++) ra[j] = *(const float4*)(Abase + j * 16);
#pragma unroll
  for (int s = 0; s < 2; s++)
#pragma unroll
    for (int j = 0; j < 4; j++) rb[s * 4 + j] = *(const float4*)(Wbase + (size_t)s * 64 * DM + j * 16);

  for (int ks = 0; ks < 16; ks++) {
    // store staged regs -> LDS (stride-72 rows: writes & reads <=2-way on banks)
#pragma unroll
    for (int j = 0; j < 4; j++) {
      u32 w2[2] = {cvtpk(ra[j].x, ra[j].y), cvtpk(ra[j].z, ra[j].w)};
      *(uint2*)&As[srw * 72 + sc0 + j * 16] = *(uint2*)w2;
    }
#pragma unroll
    for (int s = 0; s < 2; s++)
#pragma unroll
      for (int j = 0; j < 4; j++) {
        u32 w2[2] = {cvtpk(rb[s * 4 + j].x, rb[s * 4 + j].y), cvtpk(rb[s * 4 + j].z, rb[s * 4 + j].w)};
        *(uint2*)&Bs[(s * 64 + srw) * 72 + sc0 + j * 16] = *(uint2*)w2;
      }
    __syncthreads();
    if (ks < 15) {
      const int k1 = (ks + 1) * 64;
#pragma unroll
      for (int j = 0; j < 4; j++) ra[j] = *(const float4*)(Abase + k1 + j * 16);
#pragma unroll
      for (int s = 0; s < 2; s++)
#pragma unroll
        for (int j = 0; j < 4; j++)
          rb[s * 4 + j] = *(const float4*)(Wbase + (size_t)s * 64 * DM + k1 + j * 16);
    }
    short8 af[2][2], bfr[4][2];
#pragma unroll
    for (int mi = 0; mi < 2; mi++)
#pragma unroll
      for (int kk = 0; kk < 2; kk++)
        af[mi][kk] = *(const short8*)(&As[(wr * 32 + mi * 16 + lo) * 72 + kk * 32 + hi * 8]);
#pragma unroll
    for (int ni = 0; ni < 4; ni++)
#pragma unroll
      for (int kk = 0; kk < 2; kk++)
        bfr[ni][kk] = *(const short8*)(&Bs[(wc * 64 + ni * 16 + lo) * 72 + kk * 32 + hi * 8]);
    __builtin_amdgcn_s_setprio(1);
#pragma unroll
    for (int mi = 0; mi < 2; mi++)
#pragma unroll
      for (int ni = 0; ni < 4; ni++) {
        acc[mi][ni] = __builtin_amdgcn_mfma_f32_16x16x32_bf16(af[mi][0], bfr[ni][0], acc[mi][ni], 0, 0, 0);
        acc[mi][ni] = __builtin_amdgcn_mfma_f32_16x16x32_bf16(af[mi][1], bfr[ni][1], acc[mi][ni], 0, 0, 0);
      }
    __builtin_amdgcn_s_setprio(0);
    __syncthreads();
  }

  if (mode < 2) {
    // ---- RoPE epilogue -> Qr (b,h,s,d) or Kr (b,kh,s,d) ----
    const float scale = (mode == 0) ? 0.18033688f : 1.0f;  // Q: (1/8)*log2(e)
    u16* outp = (mode == 0) ? Qr : Kr;
    const int OH = (mode == 0) ? NHEADS : NKVH;
    const float sgn = (lo & 1) ? 1.0f : -1.0f;
#pragma unroll
    for (int ni = 0; ni < 4; ni++) {
      const int col = n0 + wc * 64 + ni * 16 + lo;
      const int h = col >> 6, d = col & 63, j = d >> 1;
#pragma unroll
      for (int mi = 0; mi < 2; mi++)
#pragma unroll
        for (int r = 0; r < 4; r++) {
          int row = m0 + wr * 32 + mi * 16 + hi * 4 + r;
          int srow = row & (SEQ - 1), bb = row >> 11;
          float v = acc[mi][ni][r];
          float pv = __shfl_xor(v, 1, 64);
          float c = cosb[srow * 32 + j];
          float s = sinb[srow * 32 + j];
          outp[((size_t)(bb * OH + h) * SEQ + srow) * 64 + d] = f2b((v * c + pv * s * sgn) * scale);
        }
    }
  } else {
    // ---- V epilogue: transpose via LDS [128][72] -> Vt (b,kh,d,s) ----
    u16* Tt = SH;  // 128*72 u16 = 18432 B (fits in SH)
#pragma unroll
    for (int mi = 0; mi < 2; mi++)
#pragma unroll
      for (int ni = 0; ni < 4; ni++) {
        const int cl = wc * 64 + ni * 16 + lo;   // feature 0..127
#pragma unroll
        for (int r = 0; r < 4; r++) {
          int rl = wr * 32 + mi * 16 + hi * 4 + r;  // s 0..63
          Tt[cl * 72 + rl] = f2b(acc[mi][ni][r]);
        }
      }
    __syncthreads();
    const int dl = tid >> 1;            // feature 0..127
    const int sh2 = (tid & 1) * 32;     // s-half
    const int dg = n0 + dl;
    const int kh = dg >> 6, drow = dg & 63;
    const int bb = m0 >> 11, sbase = m0 & (SEQ - 1);
    u16* dst = Vt + ((size_t)(bb * NKVH + kh) * 64 + drow) * SEQ + sbase + sh2;
#pragma unroll
    for (int i = 0; i < 4; i++)
      *(uint4*)(dst + i * 8) = *(const uint4*)&Tt[dl * 72 + sh2 + i * 8];
  }
}

// ---------------- Flash attention (unchanged from R5/R6) ----------------
__device__ __forceinline__ void softmax_pv(f32x4 (&sc)[4], float& m, float& lsp, f32x4 (&o)[4],
                                           const short8* vb0, const short8* vb1, int hi) {
  float lm = sc[0][0];
#pragma unroll
  for (int f = 0; f < 4; f++)
#pragma unroll
    for (int r = 0; r < 4; r++) lm = fmaxf(lm, sc[f][r]);
  if (__any(lm - m > 8.f)) {
    float mx = fmaxf(m, lm);
    mx = fmaxf(mx, __shfl_xor(mx, 16, 64));
    mx = fmaxf(mx, __shfl_xor(mx, 32, 64));
    float corr = exp2f(m - mx);
    m = mx;
    lsp *= corr;
    float corrq[4];
#pragma unroll
    for (int r = 0; r < 4; r++) corrq[r] = __shfl(corr, hi * 4 + r, 64);
#pragma unroll
    for (int nf = 0; nf < 4; nf++)
#pragma unroll
      for (int r = 0; r < 4; r++) o[nf][r] *= corrq[r];
  }
  float pv2[4][4];
#pragma unroll
  for (int f = 0; f < 4; f++)
#pragma unroll
    for (int r = 0; r < 4; r++) {
      pv2[f][r] = exp2f(sc[f][r] - m);
      lsp += pv2[f][r];
    }
  union { u32 u[4]; short8 s8; } pa0, pa1;
#pragma unroll
  for (int t = 0; t < 4; t++) {
    int fsel = t >> 1, r0 = 2 * (t & 1);
    pa0.u[t] = cvtpk(pv2[fsel][r0], pv2[fsel][r0 + 1]);
    pa1.u[t] = cvtpk(pv2[2 + fsel][r0], pv2[2 + fsel][r0 + 1]);
  }
  __builtin_amdgcn_s_setprio(1);
#pragma unroll
  for (int nf = 0; nf < 4; nf++) {
    o[nf] = __builtin_amdgcn_mfma_f32_16x16x32_bf16(pa0.s8, vb0[nf], o[nf], 0, 0, 0);
    o[nf] = __builtin_amdgcn_mfma_f32_16x16x32_bf16(pa1.s8, vb1[nf], o[nf], 0, 0, 0);
  }
  __builtin_amdgcn_s_setprio(0);
}

__global__ __launch_bounds__(256, 2) void attn_kernel(const u16* __restrict__ Q, const u16* __restrict__ Kb,
                                                      const u16* __restrict__ Vt, u16* __restrict__ AO) {
  __shared__ __attribute__((aligned(16))) u16 Ks[2][4096];
  __shared__ __attribute__((aligned(16))) u16 Vs[2][4096];
  const int tid = threadIdx.x;
  const int w = tid >> 6, lane = tid & 63;
  const int lo = lane & 15, hi = lane >> 4;
  const int bh = blockIdx.x;
  const int b = bh >> 4, h = bh & 15, kh = h >> 2;
  const int p = blockIdx.y;
  const int tA = p, tB = 31 - p;
  const int q0A = tA * 64 + w * 16;
  const int q0B = tB * 64 + w * 16;
  const u16* Qp = Q + (size_t)bh * SEQ * 64;
  const u16* Kp = Kb + (size_t)(b * NKVH + kh) * SEQ * 64;
  const u16* Vp = Vt + (size_t)(b * NKVH + kh) * 64 * SEQ;

  short8 qfA[2], qfB[2];
#pragma unroll
  for (int kk = 0; kk < 2; kk++) {
    qfA[kk] = *(const short8*)(Qp + (size_t)(q0A + lo) * 64 + kk * 32 + hi * 8);
    qfB[kk] = *(const short8*)(Qp + (size_t)(q0B + lo) * 64 + kk * 32 + hi * 8);
  }

  f32x4 oA[4], oB[4];
#pragma unroll
  for (int nf = 0; nf < 4; nf++) { oA[nf] = (f32x4){0.f,0.f,0.f,0.f}; oB[nf] = (f32x4){0.f,0.f,0.f,0.f}; }
  float mA = -__builtin_inff(), lspA = 0.f;
  float mB = -__builtin_inff(), lspB = 0.f;

  auto key = [](int row) { return (row & 3) | (((row >> 3) & 1) << 2); };
  auto stage = [&](int kv0, int bufi) {
#pragma unroll
    for (int s = 0; s < 2; s++) {
      int base = s * 4096 + w * 1024;
      int o2 = base + (lane << 4);
      int row = o2 >> 7;
      int gg = ((o2 >> 4) & 7) ^ key(row);
      gload16(Kp + (size_t)(kv0 + row) * 64 + gg * 8, (char*)&Ks[bufi][0] + base);
      gload16(Vp + (size_t)row * SEQ + kv0 + gg * 8, (char*)&Vs[bufi][0] + base);
    }
  };
  auto lds8 = [&](const u16* S, int row, int col8) {
    return *(const short8*)(S + row * 64 + (col8 ^ (key(row) << 3)));
  };

  int krow[4];
#pragma unroll
  for (int f = 0; f < 4; f++)
    krow[f] = 32 * (f >> 1) + 8 * (lo >> 2) + 4 * (f & 1) + (lo & 3);

  const int nt = tB + 1;
  stage(0, 0);
  __syncthreads();

  for (int c = 0; c < nt; ++c) {
    const int cur = c & 1;
    const int kv0 = c * 64;
    if (c + 1 < nt) stage(kv0 + 64, cur ^ 1);

    short8 kf0[4], kf1[4];
#pragma unroll
    for (int f = 0; f < 4; f++) {
      kf0[f] = lds8(&Ks[cur][0], krow[f], hi * 8);
      kf1[f] = lds8(&Ks[cur][0], krow[f], 32 + hi * 8);
    }
    const bool actA = (c <= tA);

    f32x4 scB[4], scA[4];
#pragma unroll
    for (int f = 0; f < 4; f++) scB[f] = (f32x4){0.f,0.f,0.f,0.f};
    __builtin_amdgcn_s_setprio(1);
#pragma unroll
    for (int f = 0; f < 4; f++) {
      scB[f] = __builtin_amdgcn_mfma_f32_16x16x32_bf16(kf0[f], qfB[0], scB[f], 0, 0, 0);
      scB[f] = __builtin_amdgcn_mfma_f32_16x16x32_bf16(kf1[f], qfB[1], scB[f], 0, 0, 0);
    }
    __builtin_amdgcn_s_setprio(0);
    if (actA) {
#pragma unroll
      for (int f = 0; f < 4; f++) scA[f] = (f32x4){0.f,0.f,0.f,0.f};
      __builtin_amdgcn_s_setprio(1);
#pragma unroll
      for (int f = 0; f < 4; f++) {
        scA[f] = __builtin_amdgcn_mfma_f32_16x16x32_bf16(kf0[f], qfA[0], scA[f], 0, 0, 0);
        scA[f] = __builtin_amdgcn_mfma_f32_16x16x32_bf16(kf1[f], qfA[1], scA[f], 0, 0, 0);
      }
      __builtin_amdgcn_s_setprio(0);
    }

    short8 vb0[4], vb1[4];
#pragma unroll
    for (int nf = 0; nf < 4; nf++) {
      vb0[nf] = lds8(&Vs[cur][0], nf * 16 + lo, hi * 8);
      vb1[nf] = lds8(&Vs[cur][0], nf * 16 + lo, 32 + hi * 8);
    }

    if (c == tB) {
#pragma unroll
      for (int f = 0; f < 4; f++) {
        int kvb = kv0 + 32 * (f >> 1) + 8 * hi + 4 * (f & 1);
#pragma unroll
        for (int r = 0; r < 4; r++)
          if (kvb + r > q0B + lo) scB[f][r] = -__builtin_inff();
      }
    }
    softmax_pv(scB, mB, lspB, oB, vb0, vb1, hi);

    if (actA) {
      if (c == tA) {
#pragma unroll
        for (int f = 0; f < 4; f++) {
          int kvb = kv0 + 32 * (f >> 1) + 8 * hi + 4 * (f & 1);
#pragma unroll
          for (int r = 0; r < 4; r++)
            if (kvb + r > q0A + lo) scA[f][r] = -__builtin_inff();
        }
      }
      softmax_pv(scA, mA, lspA, oA, vb0, vb1, hi);
    }
    __syncthreads();
  }

#pragma unroll
  for (int t2 = 0; t2 < 2; t2++) {
    float lsp = t2 ? lspB : lspA;
    const int q0 = t2 ? q0B : q0A;
    f32x4* o = t2 ? oB : oA;
    lsp += __shfl_xor(lsp, 16, 64);
    lsp += __shfl_xor(lsp, 32, 64);
    float inv = 1.0f / lsp;
    float invq[4];
#pragma unroll
    for (int r = 0; r < 4; r++) invq[r] = __shfl(inv, hi * 4 + r, 64);
#pragma unroll
    for (int nf = 0; nf < 4; nf++)
#pragma unroll
      for (int r = 0; r < 4; r++) {
        int q = q0 + hi * 4 + r;
        int d = nf * 16 + lo;
        AO[((size_t)(b * SEQ + q) * NHEADS + h) * 64 + d] = f2b(o[nf][r] * invq[r]);
      }
  }
}

// ---------------- output projection: d_out[M,1024] = AO(bf16) @ wo^T(fp32) ----------------
// grid (64, 8): M-tile 64, N-tile 128. A via global_load_lds with T21 source-swizzle.
__global__ __launch_bounds__(256) void gemm_out(const u16* __restrict__ A, const float* __restrict__ W,
                                                float* __restrict__ Out) {
  __shared__ __attribute__((aligned(16))) u16 As[4096];   // [64][64] source-swizzled
  __shared__ __attribute__((aligned(16))) u16 Bs[9216];   // [128][72]
  const int tid = threadIdx.x, lane = tid & 63, w = tid >> 6;
  const int wr = w >> 1, wc = w & 1, lo = lane & 15, hi = lane >> 4;
  const int m0 = blockIdx.x * 64, n0 = blockIdx.y * 128;
  const int crow = lane >> 3;
  const int gsw = ((lane & 7) ^ crow) << 3;   // swizzled source granule

  f32x4 acc[2][4];
#pragma unroll
  for (int i = 0; i < 2; i++)
#pragma unroll
    for (int j = 0; j < 4; j++) acc[i][j] = (f32x4){0.f, 0.f, 0.f, 0.f};

  const int srw = tid >> 2, sc0 = (tid & 3) * 4;
  const float* Wbase = W + (size_t)(n0 + srw) * DM + sc0;
  float4 rb[8];
#pragma unroll
  for (int s = 0; s < 2; s++)
#pragma unroll
    for (int j = 0; j < 4; j++) rb[s * 4 + j] = *(const float4*)(Wbase + (size_t)s * 64 * DM + j * 16);

  for (int ks = 0; ks < 16; ks++) {
    const int k0 = ks * 64;
#pragma unroll
    for (int cc = 0; cc < 2; ++cc) {
      int c = w * 2 + cc;
      gload16(A + (size_t)(m0 + c * 8 + crow) * DM + k0 + gsw, &As[c * 512]);
    }
#pragma unroll
    for (int s = 0; s < 2; s++)
#pragma unroll
      for (int j = 0; j < 4; j++) {
        u32 w2[2] = {cvtpk(rb[s * 4 + j].x, rb[s * 4 + j].y), cvtpk(rb[s * 4 + j].z, rb[s * 4 + j].w)};
        *(uint2*)&Bs[(s * 64 + srw) * 72 + sc0 + j * 16] = *(uint2*)w2;
      }
    __syncthreads();
    if (ks < 15) {
      const int k1 = k0 + 64;
#pragma unroll
      for (int s = 0; s < 2; s++)
#pragma unroll
        for (int j = 0; j < 4; j++)
          rb[s * 4 + j] = *(const float4*)(Wbase + (size_t)s * 64 * DM + k1 + j * 16);
    }
    short8 af[2][2], bfr[4][2];
#pragma unroll
    for (int mi = 0; mi < 2; mi++)
#pragma unroll
      for (int kk = 0; kk < 2; kk++)
        af[mi][kk] = *(const short8*)(&As[(wr * 32 + mi * 16 + lo) * 64 + (((kk * 4 + hi) ^ (lo & 7)) << 3)]);
#pragma unroll
    for (int ni = 0; ni < 4; ni++)
#pragma unroll
      for (int kk = 0; kk < 2; kk++)
        bfr[ni][kk] = *(const short8*)(&Bs[(wc * 64 + ni * 16 + lo) * 72 + kk * 32 + hi * 8]);
    __builtin_amdgcn_s_setprio(1);
#pragma unroll
    for (int mi = 0; mi < 2; mi++)
#pragma unroll
      for (int ni = 0; ni < 4; ni++) {
        acc[mi][ni] = __builtin_amdgcn_mfma_f32_16x16x32_bf16(af[mi][0], bfr[ni][0], acc[mi][ni], 0, 0, 0);
        acc[mi][ni] = __builtin_amdgcn_mfma_f32_16x16x32_bf16(af[mi][1], bfr[ni][1], acc[mi][ni], 0, 0, 0);
      }
    __builtin_amdgcn_s_setprio(0);
    __syncthreads();
  }

#pragma unroll
  for (int mi = 0; mi < 2; mi++)
#pragma unroll
    for (int ni = 0; ni < 4; ni++)
#pragma unroll
      for (int r = 0; r < 4; r++) {
        int row = m0 + wr * 32 + mi * 16 + hi * 4 + r;
        int col = n0 + wc * 64 + ni * 16 + lo;
        Out[(size_t)row * DM + col] = acc[mi][ni][r];
      }
}

extern "C" void kernel_launch(void* const* d_in, const int* in_sizes, int n_in,
                              void* d_out, int out_size, void* d_ws, size_t ws_size,
                              hipStream_t stream) {
  const float* query = (const float*)d_in[0];
  const float* key_ = (const float*)d_in[1];
  const float* value = (const float*)d_in[2];
  const float* fcos = (const float*)d_in[3];
  const float* fsin = (const float*)d_in[4];
  const float* wq = (const float*)d_in[5];
  const float* wk = (const float*)d_in[6];
  const float* wv = (const float*)d_in[7];
  const float* wo = (const float*)d_in[8];

  char* ws = (char*)d_ws;
  size_t off = 0;
  auto alloc = [&](size_t elems) {
    u16* p = (u16*)(ws + off);
    off = (off + elems * 2 + 255) & ~(size_t)255;
    return p;
  };
  u16* Qr = alloc((size_t)MTOK * DM);            // (b,h,s,d) rope'd + scaled
  u16* Kr = alloc((size_t)NB * NKVH * SEQ * 64); // (b,kh,s,d) rope'd
  u16* Vt = alloc((size_t)NB * NKVH * 64 * SEQ); // (b,kh,d,s)
  u16* AO = alloc((size_t)MTOK * DM);            // (b,s,h,d)

  gemm_qkv<<<dim3(64, 12), 256, 0, stream>>>(query, key_, value, wq, wk, wv,
                                             fcos, fsin, Qr, Kr, Vt);

  attn_kernel<<<dim3(NB * NHEADS, 16), 256, 0, stream>>>(Qr, Kr, Vt, AO);

  gemm_out<<<dim3(64, 8), 256, 0, stream>>>(AO, wo, (float*)d_out);
}

// Round 8
// 93.496 us; speedup vs baseline: 3.7941x; 1.0576x over previous
//
#include <hip/hip_runtime.h>

#define DM 1024
#define NHEADS 16
#define NKVH 4
#define HDIM 64
#define NB 2
#define SEQ 2048
#define MTOK (NB*SEQ)

typedef __attribute__((ext_vector_type(4))) float f32x4;
typedef __attribute__((ext_vector_type(8))) short short8;
typedef unsigned short u16;
typedef unsigned int u32;

__device__ __forceinline__ u16 f2b(float f) {
  u32 i; __builtin_memcpy(&i, &f, 4);
  u32 r = i + 0x7fffu + ((i >> 16) & 1u);
  return (u16)(r >> 16);
}
__device__ __forceinline__ u32 cvtpk(float a, float b) {  // low16=bf16(a), high16=bf16(b)
  u32 r; asm("v_cvt_pk_bf16_f32 %0, %1, %2" : "=v"(r) : "v"(a), "v"(b)); return r;
}
__device__ __forceinline__ void gload16(const void* g, void* l) {
  __builtin_amdgcn_global_load_lds((const __attribute__((address_space(1))) u32*)g,
                                   (__attribute__((address_space(3))) u32*)l, 16, 0, 0);
}

// ---------------- fused fp32 -> bf16 convert (all 7 tensors, one launch) ----------------
__device__ __forceinline__ void cvt8(const float* __restrict__ src, u16* __restrict__ dst, int i) {
  float4 a = *(const float4*)(src + i);
  float4 b = *(const float4*)(src + i + 4);
  uint4 pk;
  pk.x = cvtpk(a.x, a.y);
  pk.y = cvtpk(a.z, a.w);
  pk.z = cvtpk(b.x, b.y);
  pk.w = cvtpk(b.z, b.w);
  *(uint4*)(dst + i) = pk;
}

__global__ __launch_bounds__(256) void cvt_all(const float* __restrict__ q, const float* __restrict__ k,
                                               const float* __restrict__ v, const float* __restrict__ wq,
                                               const float* __restrict__ wk, const float* __restrict__ wv,
                                               const float* __restrict__ wo, u16* oq, u16* ok, u16* ov,
                                               u16* owq, u16* owk, u16* owv, u16* owo) {
  const int ACT = (MTOK * DM) / 2048;  // 2048 blocks per activation tensor
  const int BIG = (DM * DM) / 2048;    // 512
  const int SML = (256 * DM) / 2048;   // 128
  int bid = blockIdx.x;
  const float* s; u16* d;
  if (bid < ACT) { s = q; d = oq; }
  else if (bid < 2 * ACT) { s = k; d = ok; bid -= ACT; }
  else if (bid < 3 * ACT) { s = v; d = ov; bid -= 2 * ACT; }
  else {
    bid -= 3 * ACT;
    if (bid < BIG) { s = wq; d = owq; }
    else if (bid < 2 * BIG) { s = wo; d = owo; bid -= BIG; }
    else if (bid < 2 * BIG + SML) { s = wk; d = owk; bid -= 2 * BIG; }
    else { s = wv; d = owv; bid -= 2 * BIG + SML; }
  }
  cvt8(s, d, (bid * 256 + threadIdx.x) * 8);
}

// ---- m97-style bf16 tile staging: NR rows x 64 cols, source-swizzled (T21) ----
template<int NR>
__device__ __forceinline__ void stage_tile(const u16* __restrict__ src, int k0, u16* lds,
                                           int w, int lane) {
#pragma unroll
  for (int i = 0; i < NR / 32; i++) {
    const int base = (i * 4 + w) * 1024;          // byte offset (wave-uniform)
    const int row = (base >> 7) + (lane >> 3);    // 128B per row
    const int g = lane & 7;
    gload16(src + (size_t)row * DM + k0 + ((g ^ (row & 7)) << 3), (char*)lds + base);
  }
}
__device__ __forceinline__ short8 lds_frag(const u16* L, int row, int gr) {
  return *(const short8*)(L + row * 64 + ((gr ^ (row & 7)) << 3));
}

// ---------------- fused QKV projection GEMM (bf16) + RoPE + V-transpose ----------------
// grid (64, 12): bx = m-tile (64 rows); by 0..7 -> Q (+rope,scaled), 8..9 -> K (+rope),
// 10..11 -> V (transposed store).
__global__ __launch_bounds__(256, 3) void gemm_qkv(const u16* __restrict__ Aq, const u16* __restrict__ Ak,
                                                   const u16* __restrict__ Av, const u16* __restrict__ wq,
                                                   const u16* __restrict__ wk, const u16* __restrict__ wv,
                                                   const float* __restrict__ cosb, const float* __restrict__ sinb,
                                                   u16* __restrict__ Qr, u16* __restrict__ Kr,
                                                   u16* __restrict__ Vt) {
  __shared__ __attribute__((aligned(16))) u16 SH[12288];  // As[64][64] + Bs[128][64]
  u16* As = SH;
  u16* Bs = SH + 4096;
  const int tid = threadIdx.x, lane = tid & 63, w = tid >> 6;
  const int wr = w >> 1, wc = w & 1, lo = lane & 15, hi = lane >> 4;
  const int bx = blockIdx.x, by = blockIdx.y;
  const int m0 = bx * 64;

  const u16 *Ap, *Wp;
  int n0, mode;
  if (by < 8) { Ap = Aq; Wp = wq; n0 = by * 128; mode = 0; }
  else if (by < 10) { Ap = Ak; Wp = wk; n0 = (by - 8) * 128; mode = 1; }
  else { Ap = Av; Wp = wv; n0 = (by - 10) * 128; mode = 2; }
  const u16* Abase = Ap + (size_t)m0 * DM;
  const u16* Wbase = Wp + (size_t)n0 * DM;

  f32x4 acc[2][4];
#pragma unroll
  for (int i = 0; i < 2; i++)
#pragma unroll
    for (int j = 0; j < 4; j++) acc[i][j] = (f32x4){0.f, 0.f, 0.f, 0.f};

  for (int ks = 0; ks < 16; ks++) {
    const int k0 = ks * 64;
    stage_tile<64>(Abase, k0, As, w, lane);
    stage_tile<128>(Wbase, k0, Bs, w, lane);
    __syncthreads();
    short8 af[2][2], bfr[4][2];
#pragma unroll
    for (int mi = 0; mi < 2; mi++)
#pragma unroll
      for (int kk = 0; kk < 2; kk++)
        af[mi][kk] = lds_frag(As, wr * 32 + mi * 16 + lo, kk * 4 + hi);
#pragma unroll
    for (int ni = 0; ni < 4; ni++)
#pragma unroll
      for (int kk = 0; kk < 2; kk++)
        bfr[ni][kk] = lds_frag(Bs, wc * 64 + ni * 16 + lo, kk * 4 + hi);
    __builtin_amdgcn_s_setprio(1);
#pragma unroll
    for (int mi = 0; mi < 2; mi++)
#pragma unroll
      for (int ni = 0; ni < 4; ni++) {
        acc[mi][ni] = __builtin_amdgcn_mfma_f32_16x16x32_bf16(af[mi][0], bfr[ni][0], acc[mi][ni], 0, 0, 0);
        acc[mi][ni] = __builtin_amdgcn_mfma_f32_16x16x32_bf16(af[mi][1], bfr[ni][1], acc[mi][ni], 0, 0, 0);
      }
    __builtin_amdgcn_s_setprio(0);
    __syncthreads();
  }

  if (mode < 2) {
    // ---- RoPE epilogue -> Qr (b,h,s,d) or Kr (b,kh,s,d) ----
    const float scale = (mode == 0) ? 0.18033688f : 1.0f;  // Q: (1/8)*log2(e)
    u16* outp = (mode == 0) ? Qr : Kr;
    const int OH = (mode == 0) ? NHEADS : NKVH;
    const float sgn = (lo & 1) ? 1.0f : -1.0f;
#pragma unroll
    for (int ni = 0; ni < 4; ni++) {
      const int col = n0 + wc * 64 + ni * 16 + lo;
      const int h = col >> 6, d = col & 63, j = d >> 1;
#pragma unroll
      for (int mi = 0; mi < 2; mi++)
#pragma unroll
        for (int r = 0; r < 4; r++) {
          int row = m0 + wr * 32 + mi * 16 + hi * 4 + r;
          int srow = row & (SEQ - 1), bb = row >> 11;
          float v = acc[mi][ni][r];
          float pv = __shfl_xor(v, 1, 64);
          float c = cosb[srow * 32 + j];
          float s = sinb[srow * 32 + j];
          outp[((size_t)(bb * OH + h) * SEQ + srow) * 64 + d] = f2b((v * c + pv * s * sgn) * scale);
        }
    }
  } else {
    // ---- V epilogue: transpose via LDS [128][72] -> Vt (b,kh,d,s) ----
    u16* Tt = SH;  // 128*72 = 9216 u16 (fits in 12288)
#pragma unroll
    for (int mi = 0; mi < 2; mi++)
#pragma unroll
      for (int ni = 0; ni < 4; ni++) {
        const int cl = wc * 64 + ni * 16 + lo;   // feature 0..127
#pragma unroll
        for (int r = 0; r < 4; r++) {
          int rl = wr * 32 + mi * 16 + hi * 4 + r;  // s 0..63
          Tt[cl * 72 + rl] = f2b(acc[mi][ni][r]);
        }
      }
    __syncthreads();
    const int dl = tid >> 1;            // feature 0..127
    const int sh2 = (tid & 1) * 32;     // s-half
    const int dg = n0 + dl;
    const int kh = dg >> 6, drow = dg & 63;
    const int bb = m0 >> 11, sbase = m0 & (SEQ - 1);
    u16* dst = Vt + ((size_t)(bb * NKVH + kh) * 64 + drow) * SEQ + sbase + sh2;
#pragma unroll
    for (int i = 0; i < 4; i++)
      *(uint4*)(dst + i * 8) = *(const uint4*)&Tt[dl * 72 + sh2 + i * 8];
  }
}

// ---------------- Flash attention: swapped QK^T, P in registers, paired tiles ----------------
__device__ __forceinline__ void softmax_pv(f32x4 (&sc)[4], float& m, float& lsp, f32x4 (&o)[4],
                                           const short8* vb0, const short8* vb1, int hi) {
  float lm = sc[0][0];
#pragma unroll
  for (int f = 0; f < 4; f++)
#pragma unroll
    for (int r = 0; r < 4; r++) lm = fmaxf(lm, sc[f][r]);
  if (__any(lm - m > 8.f)) {
    float mx = fmaxf(m, lm);
    mx = fmaxf(mx, __shfl_xor(mx, 16, 64));
    mx = fmaxf(mx, __shfl_xor(mx, 32, 64));
    float corr = exp2f(m - mx);
    m = mx;
    lsp *= corr;
    float corrq[4];
#pragma unroll
    for (int r = 0; r < 4; r++) corrq[r] = __shfl(corr, hi * 4 + r, 64);
#pragma unroll
    for (int nf = 0; nf < 4; nf++)
#pragma unroll
      for (int r = 0; r < 4; r++) o[nf][r] *= corrq[r];
  }
  float pv2[4][4];
#pragma unroll
  for (int f = 0; f < 4; f++)
#pragma unroll
    for (int r = 0; r < 4; r++) {
      pv2[f][r] = exp2f(sc[f][r] - m);
      lsp += pv2[f][r];
    }
  union { u32 u[4]; short8 s8; } pa0, pa1;
#pragma unroll
  for (int t = 0; t < 4; t++) {
    int fsel = t >> 1, r0 = 2 * (t & 1);
    pa0.u[t] = cvtpk(pv2[fsel][r0], pv2[fsel][r0 + 1]);
    pa1.u[t] = cvtpk(pv2[2 + fsel][r0], pv2[2 + fsel][r0 + 1]);
  }
  __builtin_amdgcn_s_setprio(1);
#pragma unroll
  for (int nf = 0; nf < 4; nf++) {
    o[nf] = __builtin_amdgcn_mfma_f32_16x16x32_bf16(pa0.s8, vb0[nf], o[nf], 0, 0, 0);
    o[nf] = __builtin_amdgcn_mfma_f32_16x16x32_bf16(pa1.s8, vb1[nf], o[nf], 0, 0, 0);
  }
  __builtin_amdgcn_s_setprio(0);
}

__global__ __launch_bounds__(256, 2) void attn_kernel(const u16* __restrict__ Q, const u16* __restrict__ Kb,
                                                      const u16* __restrict__ Vt, u16* __restrict__ AO) {
  __shared__ __attribute__((aligned(16))) u16 Ks[2][4096];
  __shared__ __attribute__((aligned(16))) u16 Vs[2][4096];
  const int tid = threadIdx.x;
  const int w = tid >> 6, lane = tid & 63;
  const int lo = lane & 15, hi = lane >> 4;
  const int bh = blockIdx.x;
  const int b = bh >> 4, h = bh & 15, kh = h >> 2;
  const int yy = blockIdx.y;
  const int p = (yy < 8) ? yy : 23 - yy;  // per-CU uniform: nt(y)+nt(y+8)=49
  const int tA = p, tB = 31 - p;
  const int q0A = tA * 64 + w * 16;
  const int q0B = tB * 64 + w * 16;
  const u16* Qp = Q + (size_t)bh * SEQ * 64;
  const u16* Kp = Kb + (size_t)(b * NKVH + kh) * SEQ * 64;
  const u16* Vp = Vt + (size_t)(b * NKVH + kh) * 64 * SEQ;

  short8 qfA[2], qfB[2];
#pragma unroll
  for (int kk = 0; kk < 2; kk++) {
    qfA[kk] = *(const short8*)(Qp + (size_t)(q0A + lo) * 64 + kk * 32 + hi * 8);
    qfB[kk] = *(const short8*)(Qp + (size_t)(q0B + lo) * 64 + kk * 32 + hi * 8);
  }

  f32x4 oA[4], oB[4];
#pragma unroll
  for (int nf = 0; nf < 4; nf++) { oA[nf] = (f32x4){0.f,0.f,0.f,0.f}; oB[nf] = (f32x4){0.f,0.f,0.f,0.f}; }
  float mA = -__builtin_inff(), lspA = 0.f;
  float mB = -__builtin_inff(), lspB = 0.f;

  auto key = [](int row) { return (row & 3) | (((row >> 3) & 1) << 2); };
  auto stage = [&](int kv0, int bufi) {
#pragma unroll
    for (int s = 0; s < 2; s++) {
      int base = s * 4096 + w * 1024;
      int o2 = base + (lane << 4);
      int row = o2 >> 7;
      int gg = ((o2 >> 4) & 7) ^ key(row);
      gload16(Kp + (size_t)(kv0 + row) * 64 + gg * 8, (char*)&Ks[bufi][0] + base);
      gload16(Vp + (size_t)row * SEQ + kv0 + gg * 8, (char*)&Vs[bufi][0] + base);
    }
  };
  auto lds8 = [&](const u16* S, int row, int col8) {
    return *(const short8*)(S + row * 64 + (col8 ^ (key(row) << 3)));
  };

  int krow[4];
#pragma unroll
  for (int f = 0; f < 4; f++)
    krow[f] = 32 * (f >> 1) + 8 * (lo >> 2) + 4 * (f & 1) + (lo & 3);

  const int nt = tB + 1;
  stage(0, 0);
  __syncthreads();

  for (int c = 0; c < nt; ++c) {
    const int cur = c & 1;
    const int kv0 = c * 64;
    if (c + 1 < nt) stage(kv0 + 64, cur ^ 1);

    short8 kf0[4], kf1[4];
#pragma unroll
    for (int f = 0; f < 4; f++) {
      kf0[f] = lds8(&Ks[cur][0], krow[f], hi * 8);
      kf1[f] = lds8(&Ks[cur][0], krow[f], 32 + hi * 8);
    }
    const bool actA = (c <= tA);

    f32x4 scB[4], scA[4];
#pragma unroll
    for (int f = 0; f < 4; f++) scB[f] = (f32x4){0.f,0.f,0.f,0.f};
    __builtin_amdgcn_s_setprio(1);
#pragma unroll
    for (int f = 0; f < 4; f++) {
      scB[f] = __builtin_amdgcn_mfma_f32_16x16x32_bf16(kf0[f], qfB[0], scB[f], 0, 0, 0);
      scB[f] = __builtin_amdgcn_mfma_f32_16x16x32_bf16(kf1[f], qfB[1], scB[f], 0, 0, 0);
    }
    __builtin_amdgcn_s_setprio(0);
    if (actA) {
#pragma unroll
      for (int f = 0; f < 4; f++) scA[f] = (f32x4){0.f,0.f,0.f,0.f};
      __builtin_amdgcn_s_setprio(1);
#pragma unroll
      for (int f = 0; f < 4; f++) {
        scA[f] = __builtin_amdgcn_mfma_f32_16x16x32_bf16(kf0[f], qfA[0], scA[f], 0, 0, 0);
        scA[f] = __builtin_amdgcn_mfma_f32_16x16x32_bf16(kf1[f], qfA[1], scA[f], 0, 0, 0);
      }
      __builtin_amdgcn_s_setprio(0);
    }

    short8 vb0[4], vb1[4];
#pragma unroll
    for (int nf = 0; nf < 4; nf++) {
      vb0[nf] = lds8(&Vs[cur][0], nf * 16 + lo, hi * 8);
      vb1[nf] = lds8(&Vs[cur][0], nf * 16 + lo, 32 + hi * 8);
    }

    if (c == tB) {
#pragma unroll
      for (int f = 0; f < 4; f++) {
        int kvb = kv0 + 32 * (f >> 1) + 8 * hi + 4 * (f & 1);
#pragma unroll
        for (int r = 0; r < 4; r++)
          if (kvb + r > q0B + lo) scB[f][r] = -__builtin_inff();
      }
    }
    softmax_pv(scB, mB, lspB, oB, vb0, vb1, hi);

    if (actA) {
      if (c == tA) {
#pragma unroll
        for (int f = 0; f < 4; f++) {
          int kvb = kv0 + 32 * (f >> 1) + 8 * hi + 4 * (f & 1);
#pragma unroll
          for (int r = 0; r < 4; r++)
            if (kvb + r > q0A + lo) scA[f][r] = -__builtin_inff();
        }
      }
      softmax_pv(scA, mA, lspA, oA, vb0, vb1, hi);
    }
    __syncthreads();
  }

#pragma unroll
  for (int t2 = 0; t2 < 2; t2++) {
    float lsp = t2 ? lspB : lspA;
    const int q0 = t2 ? q0B : q0A;
    f32x4* o = t2 ? oB : oA;
    lsp += __shfl_xor(lsp, 16, 64);
    lsp += __shfl_xor(lsp, 32, 64);
    float inv = 1.0f / lsp;
    float invq[4];
#pragma unroll
    for (int r = 0; r < 4; r++) invq[r] = __shfl(inv, hi * 4 + r, 64);
#pragma unroll
    for (int nf = 0; nf < 4; nf++)
#pragma unroll
      for (int r = 0; r < 4; r++) {
        int q = q0 + hi * 4 + r;
        int d = nf * 16 + lo;
        AO[((size_t)(b * SEQ + q) * NHEADS + h) * 64 + d] = f2b(o[nf][r] * invq[r]);
      }
  }
}

// ---------------- output projection: d_out[M,1024] = AO(bf16) @ wo^T(bf16) ----------------
// grid (64, 8): bx = m-tile (64 rows), by = col-tile (128)
__global__ __launch_bounds__(256, 2) void gemm_out(const u16* __restrict__ A, const u16* __restrict__ W,
                                                   float* __restrict__ Out) {
  __shared__ __attribute__((aligned(16))) u16 SH[12288];
  u16* As = SH;
  u16* Bs = SH + 4096;
  const int tid = threadIdx.x, lane = tid & 63, w = tid >> 6;
  const int wr = w >> 1, wc = w & 1, lo = lane & 15, hi = lane >> 4;
  const int m0 = blockIdx.x * 64, n0 = blockIdx.y * 128;
  const u16* Abase = A + (size_t)m0 * DM;
  const u16* Wbase = W + (size_t)n0 * DM;

  f32x4 acc[2][4];
#pragma unroll
  for (int i = 0; i < 2; i++)
#pragma unroll
    for (int j = 0; j < 4; j++) acc[i][j] = (f32x4){0.f, 0.f, 0.f, 0.f};

  for (int ks = 0; ks < 16; ks++) {
    const int k0 = ks * 64;
    stage_tile<64>(Abase, k0, As, w, lane);
    stage_tile<128>(Wbase, k0, Bs, w, lane);
    __syncthreads();
    short8 af[2][2], bfr[4][2];
#pragma unroll
    for (int mi = 0; mi < 2; mi++)
#pragma unroll
      for (int kk = 0; kk < 2; kk++)
        af[mi][kk] = lds_frag(As, wr * 32 + mi * 16 + lo, kk * 4 + hi);
#pragma unroll
    for (int ni = 0; ni < 4; ni++)
#pragma unroll
      for (int kk = 0; kk < 2; kk++)
        bfr[ni][kk] = lds_frag(Bs, wc * 64 + ni * 16 + lo, kk * 4 + hi);
    __builtin_amdgcn_s_setprio(1);
#pragma unroll
    for (int mi = 0; mi < 2; mi++)
#pragma unroll
      for (int ni = 0; ni < 4; ni++) {
        acc[mi][ni] = __builtin_amdgcn_mfma_f32_16x16x32_bf16(af[mi][0], bfr[ni][0], acc[mi][ni], 0, 0, 0);
        acc[mi][ni] = __builtin_amdgcn_mfma_f32_16x16x32_bf16(af[mi][1], bfr[ni][1], acc[mi][ni], 0, 0, 0);
      }
    __builtin_amdgcn_s_setprio(0);
    __syncthreads();
  }

#pragma unroll
  for (int mi = 0; mi < 2; mi++)
#pragma unroll
    for (int ni = 0; ni < 4; ni++)
#pragma unroll
      for (int r = 0; r < 4; r++) {
        int row = m0 + wr * 32 + mi * 16 + hi * 4 + r;
        int col = n0 + wc * 64 + ni * 16 + lo;
        Out[(size_t)row * DM + col] = acc[mi][ni][r];
      }
}

extern "C" void kernel_launch(void* const* d_in, const int* in_sizes, int n_in,
                              void* d_out, int out_size, void* d_ws, size_t ws_size,
                              hipStream_t stream) {
  const float* query = (const float*)d_in[0];
  const float* key_ = (const float*)d_in[1];
  const float* value = (const float*)d_in[2];
  const float* fcos = (const float*)d_in[3];
  const float* fsin = (const float*)d_in[4];
  const float* wq = (const float*)d_in[5];
  const float* wk = (const float*)d_in[6];
  const float* wv = (const float*)d_in[7];
  const float* wo = (const float*)d_in[8];

  char* ws = (char*)d_ws;
  size_t off = 0;
  auto alloc = [&](size_t elems) {
    u16* p = (u16*)(ws + off);
    off = (off + elems * 2 + 255) & ~(size_t)255;
    return p;
  };
  u16* qf = alloc((size_t)MTOK * DM);
  u16* kf = alloc((size_t)MTOK * DM);
  u16* vf = alloc((size_t)MTOK * DM);
  u16* wqf = alloc((size_t)DM * DM);
  u16* wkf = alloc((size_t)256 * DM);
  u16* wvf = alloc((size_t)256 * DM);
  u16* wof = alloc((size_t)DM * DM);
  u16* Qr = alloc((size_t)MTOK * DM);            // (b,h,s,d) rope'd + scaled
  u16* Kr = alloc((size_t)NB * NKVH * SEQ * 64); // (b,kh,s,d) rope'd
  u16* Vt = alloc((size_t)NB * NKVH * 64 * SEQ); // (b,kh,d,s)
  u16* AO = alloc((size_t)MTOK * DM);            // (b,s,h,d)

  cvt_all<<<3 * 2048 + 1280, 256, 0, stream>>>(query, key_, value, wq, wk, wv, wo,
                                               qf, kf, vf, wqf, wkf, wvf, wof);

  gemm_qkv<<<dim3(64, 12), 256, 0, stream>>>(qf, kf, vf, wqf, wkf, wvf,
                                             fcos, fsin, Qr, Kr, Vt);

  attn_kernel<<<dim3(NB * NHEADS, 16), 256, 0, stream>>>(Qr, Kr, Vt, AO);

  gemm_out<<<dim3(64, 8), 256, 0, stream>>>(AO, wof, (float*)d_out);
}